// Round 10
// baseline (287.964 us; speedup 1.0000x reference)
//
#include <hip/hip_runtime.h>
#include <math.h>

#define FB 512
#define TB 256
#define PLANE (FB * TB)
typedef long long i64;
typedef _Float16 f16;
typedef _Float16 f16x8 __attribute__((ext_vector_type(8)));
typedef _Float16 f16x4 __attribute__((ext_vector_type(4)));
typedef float f32x4 __attribute__((ext_vector_type(4)));

#define MFMA16(a, b, c) __builtin_amdgcn_mfma_f32_16x16x32_f16(a, b, c, 0, 0, 0)

// ================= role-split prologue: transpose_cvt || weff || beff ========
// bids [0,8192): x f32 [f][t] -> f16 [t][f]; [8192,9216): Weff=W2@W1; last 2: beff
__global__ __launch_bounds__(256) void k_pre(const float* __restrict__ X,
                                             f16* __restrict__ O,
                                             const float* __restrict__ W1,
                                             const float* __restrict__ W2,
                                             f16* __restrict__ Weff,
                                             const float* __restrict__ b1,
                                             const float* __restrict__ b2,
                                             float* __restrict__ beff) {
    __shared__ float ld[64][65];
    const int bid = blockIdx.x;
    const int tid = threadIdx.x;
    if (bid < 8192) {
        const int p = bid >> 5;
        const int f0 = ((bid >> 2) & 7) * 64, t0 = (bid & 3) * 64;
        const float* src = X + (i64)p * PLANE;
        f16* dst = O + (i64)p * PLANE;
        const int lrr = tid >> 4, lc = (tid & 15) * 4;
        // prefetch all 4 rows into regs (ILP), then LDS
        const float4 v0 = *(const float4*)&src[(i64)(f0 + lrr + 0) * TB + t0 + lc];
        const float4 v1 = *(const float4*)&src[(i64)(f0 + lrr + 16) * TB + t0 + lc];
        const float4 v2 = *(const float4*)&src[(i64)(f0 + lrr + 32) * TB + t0 + lc];
        const float4 v3 = *(const float4*)&src[(i64)(f0 + lrr + 48) * TB + t0 + lc];
        ld[lrr + 0][lc + 0] = v0.x; ld[lrr + 0][lc + 1] = v0.y;
        ld[lrr + 0][lc + 2] = v0.z; ld[lrr + 0][lc + 3] = v0.w;
        ld[lrr + 16][lc + 0] = v1.x; ld[lrr + 16][lc + 1] = v1.y;
        ld[lrr + 16][lc + 2] = v1.z; ld[lrr + 16][lc + 3] = v1.w;
        ld[lrr + 32][lc + 0] = v2.x; ld[lrr + 32][lc + 1] = v2.y;
        ld[lrr + 32][lc + 2] = v2.z; ld[lrr + 32][lc + 3] = v2.w;
        ld[lrr + 48][lc + 0] = v3.x; ld[lrr + 48][lc + 1] = v3.y;
        ld[lrr + 48][lc + 2] = v3.z; ld[lrr + 48][lc + 3] = v3.w;
        __syncthreads();
        // coalesced f16x8 stores: lane covers 16B contiguous of one dst row
        const int tr2 = tid >> 3, fc = (tid & 7) * 8;
#pragma unroll
        for (int pass = 0; pass < 2; ++pass) {
            const int t = tr2 + pass * 32;
            f16x8 o;
#pragma unroll
            for (int j = 0; j < 8; ++j) o[j] = (f16)ld[fc + j][t];
            *(f16x8*)&dst[(i64)(t0 + t) * FB + f0 + fc] = o;
        }
    } else if (bid < 9216) {
        const int w = bid - 8192;
        const int m = (w >> 3) * 4 + (tid >> 6);
        const int k = (w & 7) * 64 + (tid & 63);
        const float* w2r = W2 + (i64)m * FB;
        float acc = 0.f;
#pragma unroll 4
        for (int j = 0; j < FB; ++j) acc = fmaf(w2r[j], W1[(i64)j * FB + k], acc);
        Weff[(i64)m * FB + k] = (f16)acc;
    } else {
        const int m = (bid - 9216) * 256 + tid;
        const float* w2r = W2 + (i64)m * FB;
        float acc = b2[m];
#pragma unroll 4
        for (int k = 0; k < FB; ++k) acc = fmaf(w2r[k], b1[k], acc);
        beff[m] = acc;
    }
}

// ---------- real MFMA GEMM: Out[t][m] (f16) = sum_k A[m][k]*In[t][k] + bias[m]
__global__ __launch_bounds__(256, 2) void k_rgemm(const f16* __restrict__ A,
                                                  const f16* __restrict__ In,
                                                  const float* __restrict__ bias,
                                                  f16* __restrict__ Out) {
    __shared__ f16 Asx[128][40], Bsx[128][40];
    const int slab = blockIdx.z;
    const f16* Bsrc = In + (i64)slab * PLANE;
    f16* Odst = Out + (i64)slab * PLANE;
    const int t0 = blockIdx.x * 128, m0 = blockIdx.y * 128;
    const int tid = threadIdx.x;
    const int wave = tid >> 6, lane = tid & 63;
    const int wm = wave >> 1, wn = wave & 1;
    const int lr = lane & 15, lg = lane >> 4;
    const int srow = tid >> 2, sgrp = (tid & 3) * 8;

    f32x4 acc[4][4] = {};
    f16x8 nA[2], nB[2];
#pragma unroll
    for (int i = 0; i < 2; ++i) {
        const int row = i * 64 + srow;
        nA[i] = *(const f16x8*)(A + (i64)(m0 + row) * FB + sgrp);
        nB[i] = *(const f16x8*)(Bsrc + (i64)(t0 + row) * FB + sgrp);
    }
#pragma unroll
    for (int i = 0; i < 2; ++i) {
        const int row = i * 64 + srow;
        *(f16x8*)&Asx[row][sgrp] = nA[i];
        *(f16x8*)&Bsx[row][sgrp] = nB[i];
    }
    __syncthreads();

#pragma unroll 1
    for (int kt = 0; kt < 16; ++kt) {
        if (kt < 15) {
            const int k0 = (kt + 1) * 32;
#pragma unroll
            for (int i = 0; i < 2; ++i) {
                const int row = i * 64 + srow;
                nA[i] = *(const f16x8*)(A + (i64)(m0 + row) * FB + k0 + sgrp);
                nB[i] = *(const f16x8*)(Bsrc + (i64)(t0 + row) * FB + k0 + sgrp);
            }
        }
        f16x8 aA[4], bB[4];
#pragma unroll
        for (int mf = 0; mf < 4; ++mf)
            aA[mf] = *(const f16x8*)&Asx[wm * 64 + mf * 16 + lr][lg * 8];
#pragma unroll
        for (int nf = 0; nf < 4; ++nf)
            bB[nf] = *(const f16x8*)&Bsx[wn * 64 + nf * 16 + lr][lg * 8];
#pragma unroll
        for (int nf = 0; nf < 4; ++nf)
#pragma unroll
            for (int mf = 0; mf < 4; ++mf)
                acc[mf][nf] = MFMA16(aA[mf], bB[nf], acc[mf][nf]);
        __syncthreads();
        if (kt < 15) {
#pragma unroll
            for (int i = 0; i < 2; ++i) {
                const int row = i * 64 + srow;
                *(f16x8*)&Asx[row][sgrp] = nA[i];
                *(f16x8*)&Bsx[row][sgrp] = nB[i];
            }
        }
        __syncthreads();
    }

#pragma unroll
    for (int mf = 0; mf < 4; ++mf) {
        const int m = m0 + wm * 64 + mf * 16 + lg * 4;
        const float4 bv = *(const float4*)&bias[m];
        const float bb[4] = {bv.x, bv.y, bv.z, bv.w};
#pragma unroll
        for (int nf = 0; nf < 4; ++nf) {
            const int t = t0 + wn * 64 + nf * 16 + lr;
            f16x4 o;
#pragma unroll
            for (int r = 0; r < 4; ++r) o[r] = (f16)(acc[mf][nf][r] + bb[r]);
            *(f16x4*)&Odst[(i64)t * FB + m] = o;
        }
    }
}

// ================= fused softmax + conjFFT/mul/FFT, radix-8 three-step =======
// FFT arrangement: z[p] at (lane=p%64, reg=p/64). Global I/O is CONTIGUOUS
// (16B/lane); pre-/post-transposes through the per-wave LDS buffer marshal
// between (lane=p/8, reg=p%8) I/O layout and the FFT layout. All LDS phases
// verified conflict-free per-8-lane-group (idx mod 8 distinct).

#define TWO_PI_OVER_512 0.012271846303085129f
#define TWO_PI_OVER_64 0.0981747704246810387f
#define R2C 0.70710678118654752f

template <int SGN>
__device__ __forceinline__ void fft8(float xr[8], float xi[8]) {
    const float sg = (float)SGN;   // W8 = e^{SGN*i*2pi/8}
    float t0r = xr[0] + xr[4], t0i = xi[0] + xi[4];
    float u0r = xr[0] - xr[4], u0i = xi[0] - xi[4];
    float t1r = xr[1] + xr[5], t1i = xi[1] + xi[5];
    float d1r = xr[1] - xr[5], d1i = xi[1] - xi[5];
    float u1r = R2C * (d1r - sg * d1i), u1i = R2C * (sg * d1r + d1i);
    float t2r = xr[2] + xr[6], t2i = xi[2] + xi[6];
    float d2r = xr[2] - xr[6], d2i = xi[2] - xi[6];
    float u2r = -sg * d2i, u2i = sg * d2r;
    float t3r = xr[3] + xr[7], t3i = xi[3] + xi[7];
    float d3r = xr[3] - xr[7], d3i = xi[3] - xi[7];
    float u3r = -R2C * (d3r + sg * d3i), u3i = R2C * (sg * d3r - d3i);
    float p0r = t0r + t2r, p0i = t0i + t2i, q0r = t0r - t2r, q0i = t0i - t2i;
    float p1r = t1r + t3r, p1i = t1i + t3i;
    float q1r = -sg * (t1i - t3i), q1i = sg * (t1r - t3r);
    float p2r = u0r + u2r, p2i = u0i + u2i, q2r = u0r - u2r, q2i = u0i - u2i;
    float p3r = u1r + u3r, p3i = u1i + u3i;
    float q3r = -sg * (u1i - u3i), q3i = sg * (u1r - u3r);
    xr[0] = p0r + p1r; xi[0] = p0i + p1i;
    xr[4] = p0r - p1r; xi[4] = p0i - p1i;
    xr[2] = q0r + q1r; xi[2] = q0i + q1i;
    xr[6] = q0r - q1r; xi[6] = q0i - q1i;
    xr[1] = p2r + p3r; xi[1] = p2i + p3i;
    xr[5] = p2r - p3r; xi[5] = p2i - p3i;
    xr[3] = q2r + q3r; xi[3] = q2i + q3i;
    xr[7] = q2r - q3r; xi[7] = q2i - q3i;
}

template <int SGN>
__device__ __forceinline__ void fft512x2(float ar[8], float ai[8],
                                         float br[8], float bi[8], int lane,
                                         float4* __restrict__ L,
                                         const float w1c[7], const float w1s[7],
                                         const float w2c[7], const float w2s[7]) {
    const float sg = (float)SGN;
    fft8<SGN>(ar, ai);
    fft8<SGN>(br, bi);
#pragma unroll
    for (int m = 1; m < 8; ++m) {
        const float wc = w1c[m - 1], ws = sg * w1s[m - 1];
        float tr = ar[m], ti = ai[m];
        ar[m] = tr * wc - ti * ws; ai[m] = tr * ws + ti * wc;
        tr = br[m]; ti = bi[m];
        br[m] = tr * wc - ti * ws; bi[m] = tr * ws + ti * wc;
    }
    // transpose 1: linear write lane*9+m ; permuted read (a8+8b8)*9+m8
#pragma unroll
    for (int m = 0; m < 8; ++m)
        L[lane * 9 + m] = make_float4(ar[m], ai[m], br[m], bi[m]);
    {
        const int a8 = lane & 7, m8 = lane >> 3;
#pragma unroll
        for (int b8 = 0; b8 < 8; ++b8) {
            const float4 v = L[(a8 + 8 * b8) * 9 + m8];
            ar[b8] = v.x; ai[b8] = v.y; br[b8] = v.z; bi[b8] = v.w;
        }
    }
    fft8<SGN>(ar, ai);
    fft8<SGN>(br, bi);
#pragma unroll
    for (int n = 1; n < 8; ++n) {
        const float wc = w2c[n - 1], ws = sg * w2s[n - 1];
        float tr = ar[n], ti = ai[n];
        ar[n] = tr * wc - ti * ws; ai[n] = tr * ws + ti * wc;
        tr = br[n]; ti = bi[n];
        br[n] = tr * wc - ti * ws; bi[n] = tr * ws + ti * wc;
    }
    // transpose 2: scatter write (m+8n)*9+a ; linear read lane*9+j
    {
        const int a2 = lane & 7, m2 = lane >> 3;
#pragma unroll
        for (int n = 0; n < 8; ++n)
            L[(m2 + 8 * n) * 9 + a2] = make_float4(ar[n], ai[n], br[n], bi[n]);
    }
#pragma unroll
    for (int j = 0; j < 8; ++j) {
        const float4 v = L[lane * 9 + j];
        ar[j] = v.x; ai[j] = v.y; br[j] = v.z; bi[j] = v.w;
    }
    fft8<SGN>(ar, ai);
    fft8<SGN>(br, bi);
}

__device__ __forceinline__ float wave_max(float v) {
#pragma unroll
    for (int m = 1; m <= 32; m <<= 1) v = fmaxf(v, __shfl_xor(v, m));
    return v;
}
__device__ __forceinline__ float wave_sum(float v) {
#pragma unroll
    for (int m = 1; m <= 32; m <<= 1) v += __shfl_xor(v, m);
    return v;
}

__device__ __forceinline__ void softmax8(float w[8]) {
    float mx = w[0];
#pragma unroll
    for (int j = 1; j < 8; ++j) mx = fmaxf(mx, w[j]);
    mx = wave_max(mx);
    float sm = 0.f;
#pragma unroll
    for (int j = 0; j < 8; ++j) { w[j] = __expf(w[j] - mx); sm += w[j]; }
    sm = wave_sum(sm);
    const float inv = 1.0f / sm;
#pragma unroll
    for (int j = 0; j < 8; ++j) w[j] *= inv;
}

// load 4 contiguous f16x8 arrays for one t-row, convert+marshal to FFT layout:
// loaded (srcLane, j) holds p = 8*srcLane + j; stored L[srcLane*9+j]; lane M
// reads p = M + 64v at idx (8v + (M>>3))*9 + (M&7). All phases conflict-free.
__device__ __forceinline__ void load_marshal(const f16* __restrict__ Hre,
                                             const f16* __restrict__ Him,
                                             const f16* __restrict__ Wre,
                                             const f16* __restrict__ Wim,
                                             i64 rowbase, int lane,
                                             float4* __restrict__ L,
                                             float hr[8], float hi2[8],
                                             float wr[8], float wi[8]) {
    const f16x8 vhr = *(const f16x8*)(Hre + rowbase + 8 * lane);
    const f16x8 vhi = *(const f16x8*)(Him + rowbase + 8 * lane);
    const f16x8 vwr = *(const f16x8*)(Wre + rowbase + 8 * lane);
    const f16x8 vwi = *(const f16x8*)(Wim + rowbase + 8 * lane);
#pragma unroll
    for (int j = 0; j < 8; ++j)
        L[lane * 9 + j] = make_float4((float)vhr[j], (float)vhi[j],
                                      (float)vwr[j], (float)vwi[j]);
    const int c = lane >> 3, q = lane & 7;
#pragma unroll
    for (int v = 0; v < 8; ++v) {
        const float4 f4 = L[(8 * v + c) * 9 + q];
        hr[v] = f4.x; hi2[v] = f4.y; wr[v] = f4.z; wi[v] = f4.w;
    }
}

// fftconv body for one block: t-block tblk (0..31), plane-pair cs, chunk-local conv
__device__ __forceinline__ void fftconv_block(const f16* __restrict__ xh,
                                              const f16* __restrict__ logits,
                                              float* __restrict__ conv,
                                              int tblk, int cs, int chunkoff,
                                              int wave, int lane, float4* L) {
    const int b = cs >> 4, d = cs & 15;
    const int pre = b * 32 + d;
    const int pim = pre + 16;

    float w1c[7], w1s[7], w2c[7], w2s[7];
    {
        float s1, c1;
        __sincosf((float)lane * TWO_PI_OVER_512, &s1, &c1);
        w1c[0] = c1; w1s[0] = s1;
#pragma unroll
        for (int m = 1; m < 7; ++m) {
            const float pc = w1c[m - 1], ps = w1s[m - 1];
            w1c[m] = pc * c1 - ps * s1;
            w1s[m] = pc * s1 + ps * c1;
        }
        float s2, c2;
        __sincosf((float)(lane & 7) * TWO_PI_OVER_64, &s2, &c2);
        w2c[0] = c2; w2s[0] = s2;
#pragma unroll
        for (int n = 1; n < 7; ++n) {
            const float pc = w2c[n - 1], ps = w2s[n - 1];
            w2c[n] = pc * c2 - ps * s2;
            w2s[n] = pc * s2 + ps * c2;
        }
    }

    const f16* Hre = xh + (i64)pre * PLANE;
    const f16* Him = xh + (i64)pim * PLANE;
    const f16* Wre = logits + (i64)pre * PLANE;
    const f16* Wim = logits + (i64)pim * PLANE;
    float* Cre = conv + (i64)(pre - chunkoff) * PLANE;
    float* Cim = conv + (i64)(pim - chunkoff) * PLANE;

    const int t1a = tblk * 8 + wave * 2;

    float p0r[8], p0i[8], p1r[8], p1i[8];
    {
        float hr[8], hi2[8], wr[8], wi[8];
        load_marshal(Hre, Him, Wre, Wim, (i64)t1a * FB, lane, L, hr, hi2, wr, wi);
        softmax8(wr);
        softmax8(wi);
        fft512x2<1>(hr, hi2, wr, wi, lane, L, w1c, w1s, w2c, w2s);
#pragma unroll
        for (int j = 0; j < 8; ++j) {
            p0r[j] = (hr[j] * wr[j] - hi2[j] * wi[j]) * (1.0f / 512.0f);
            p0i[j] = (hr[j] * wi[j] + hi2[j] * wr[j]) * (1.0f / 512.0f);
        }
    }
    {
        float hr[8], hi2[8], wr[8], wi[8];
        load_marshal(Hre, Him, Wre, Wim, (i64)(t1a + 1) * FB, lane, L, hr, hi2, wr, wi);
        softmax8(wr);
        softmax8(wi);
        fft512x2<1>(hr, hi2, wr, wi, lane, L, w1c, w1s, w2c, w2s);
#pragma unroll
        for (int j = 0; j < 8; ++j) {
            p1r[j] = (hr[j] * wr[j] - hi2[j] * wi[j]) * (1.0f / 512.0f);
            p1i[j] = (hr[j] * wi[j] + hi2[j] * wr[j]) * (1.0f / 512.0f);
        }
    }
    fft512x2<-1>(p0r, p0i, p1r, p1i, lane, L, w1c, w1s, w2c, w2s);

    // post-transpose: scatter write (b+8s)*9+a ; linear read lane*9+j.
    // After read, lane M holds p = 8M+j -> all stores contiguous 16B/lane.
    {
        const int a = lane & 7, bq = lane >> 3;
#pragma unroll
        for (int s = 0; s < 8; ++s)
            L[(bq + 8 * s) * 9 + a] = make_float4(p0r[s], p0i[s], p1r[s], p1i[s]);
    }
    float4 g[8];
#pragma unroll
    for (int j = 0; j < 8; ++j) g[j] = L[lane * 9 + j];
    float* C0r = Cre + (i64)t1a * FB + 8 * lane;
    float* C0i = Cim + (i64)t1a * FB + 8 * lane;
    float* C1r = Cre + (i64)(t1a + 1) * FB + 8 * lane;
    float* C1i = Cim + (i64)(t1a + 1) * FB + 8 * lane;
    *(float4*)(C0r + 0) = make_float4(g[0].x, g[1].x, g[2].x, g[3].x);
    *(float4*)(C0r + 4) = make_float4(g[4].x, g[5].x, g[6].x, g[7].x);
    *(float4*)(C0i + 0) = make_float4(g[0].y, g[1].y, g[2].y, g[3].y);
    *(float4*)(C0i + 4) = make_float4(g[4].y, g[5].y, g[6].y, g[7].y);
    *(float4*)(C1r + 0) = make_float4(g[0].z, g[1].z, g[2].z, g[3].z);
    *(float4*)(C1r + 4) = make_float4(g[4].z, g[5].z, g[6].z, g[7].z);
    *(float4*)(C1i + 0) = make_float4(g[0].w, g[1].w, g[2].w, g[3].w);
    *(float4*)(C1i + 4) = make_float4(g[4].w, g[5].w, g[6].w, g[7].w);
}

// transpose_out body: f32 [t][f] chunk plane p -> f32 [f][t] out plane p+pbase
__device__ __forceinline__ void transpose_block(const float* __restrict__ C,
                                                float* __restrict__ O,
                                                int tb, int fb, int p, int pbase,
                                                int tid, float (*ld)[65]) {
    const float* src = C + (i64)p * PLANE;
    float* dst = O + (i64)(p + pbase) * PLANE;
    const int t0 = tb * 64, f0 = fb * 64;
    const int lrr = tid >> 4, lc = (tid & 15) * 4;
#pragma unroll
    for (int i = 0; i < 4; ++i) {
        float4 v = *(const float4*)&src[(i64)(t0 + lrr + i * 16) * FB + f0 + lc];
        ld[lc + 0][lrr + i * 16] = v.x;
        ld[lc + 1][lrr + i * 16] = v.y;
        ld[lc + 2][lrr + i * 16] = v.z;
        ld[lc + 3][lrr + i * 16] = v.w;
    }
    __syncthreads();
    const int fr = tid >> 4, tc = (tid & 15) * 4;
#pragma unroll
    for (int i = 0; i < 4; ++i) {
        const int f = fr + i * 16;
        float4 o;
        o.x = ld[f][tc + 0]; o.y = ld[f][tc + 1];
        o.z = ld[f][tc + 2]; o.w = ld[f][tc + 3];
        *(float4*)&dst[(i64)(f0 + f) * TB + t0 + tc] = o;
    }
}

// ---------- chunk-0 fftconv (pairs 0..63 -> conv0)
__global__ __launch_bounds__(256, 2) void k_fftconv(const f16* __restrict__ xh,
                                                    const f16* __restrict__ logits,
                                                    float* __restrict__ conv) {
    __shared__ float4 LDS[4][576];
    const int wave = threadIdx.x >> 6, lane = threadIdx.x & 63;
    fftconv_block(xh, logits, conv, blockIdx.x, blockIdx.y, 0, wave, lane, LDS[wave]);
}

// ---------- role-split mid: fftconv(pairs 64..127 -> conv1) || transpose(conv0 -> out)
__global__ __launch_bounds__(256, 2) void k_mid(const f16* __restrict__ xh,
                                                const f16* __restrict__ logits,
                                                float* __restrict__ conv1,
                                                const float* __restrict__ conv0,
                                                float* __restrict__ out) {
    __shared__ __align__(16) char raw[36864];
    const int bid = blockIdx.x;
    const int tid = threadIdx.x;
    if (bid < 2048) {
        const int wave = tid >> 6, lane = tid & 63;
        float4* L = (float4*)raw + wave * 576;
        fftconv_block(xh, logits, conv1, bid & 31, 64 + (bid >> 5), 128, wave, lane, L);
    } else {
        const int w = bid - 2048;
        float (*ld)[65] = (float(*)[65])raw;
        transpose_block(conv0, out, w & 3, (w >> 2) & 7, w >> 5, 0, tid, ld);
    }
}

// ---------- final transpose (conv1 -> out planes 128..255)
__global__ __launch_bounds__(256) void k_transpose_out(const float* __restrict__ C,
                                                       float* __restrict__ O,
                                                       int pbase) {
    __shared__ float ld[64][65];
    transpose_block(C, O, blockIdx.x, blockIdx.y, blockIdx.z, pbase, threadIdx.x, ld);
}

extern "C" void kernel_launch(void* const* d_in, const int* in_sizes, int n_in,
                              void* d_out, int out_size, void* d_ws, size_t ws_size,
                              hipStream_t stream) {
    (void)in_sizes; (void)n_in; (void)out_size; (void)ws_size;
    const float* x = (const float*)d_in[0];
    const float* W1 = (const float*)d_in[1];
    const float* b1 = (const float*)d_in[2];
    const float* W2 = (const float*)d_in[3];
    const float* b2 = (const float*)d_in[4];
    float* out = (float*)d_out;

    char* ws = (char*)d_ws;
    const i64 TENB = (i64)67108864;                       // f16 tensor bytes / f32 half-tensor bytes
    f16* Weff = (f16*)(ws);                               // 512 KB
    float* beff = (float*)(ws + 524288);                  // 4 KB pad
    f16* xh = (f16*)(ws + 528384);                        // 67.1 MB
    f16* logits = (f16*)(ws + 528384 + TENB);             // 67.1 MB
    float* conv0 = (float*)(ws + 528384 + 2 * TENB);      // 67.1 MB
    float* conv1 = (float*)(ws + 528384 + 3 * TENB);      // 67.1 MB  (ws >= 269 MB proven r7)

    // L1: transpose_cvt || Weff=W2@W1 || beff=W2@b1+b2
    k_pre<<<dim3(9218), dim3(256), 0, stream>>>(x, xh, W1, W2, Weff, b1, b2, beff);
    // L2: logits = Weff @ X + beff
    k_rgemm<<<dim3(TB / 128, FB / 128, 256), dim3(256), 0, stream>>>(Weff, xh, beff, logits);
    // L3: chunk-0 fftconv -> conv0
    k_fftconv<<<dim3(32, 64), dim3(256), 0, stream>>>(xh, logits, conv0);
    // L4: chunk-1 fftconv -> conv1  ||  transpose conv0 -> out[0:128]
    k_mid<<<dim3(6144), dim3(256), 0, stream>>>(xh, logits, conv1, conv0, out);
    // L5: transpose conv1 -> out[128:256]
    k_transpose_out<<<dim3(4, 8, 128), dim3(256), 0, stream>>>(conv1, out, 128);
}

// Round 11
// 261.203 us; speedup vs baseline: 1.1025x; 1.1025x over previous
//
#include <hip/hip_runtime.h>
#include <math.h>

#define FB 512
#define TB 256
#define PLANE (FB * TB)
typedef long long i64;
typedef _Float16 f16;
typedef _Float16 f16x8 __attribute__((ext_vector_type(8)));
typedef _Float16 f16x4 __attribute__((ext_vector_type(4)));
typedef float f32x4 __attribute__((ext_vector_type(4)));

#define MFMA16(a, b, c) __builtin_amdgcn_mfma_f32_16x16x32_f16(a, b, c, 0, 0, 0)

// ---------- generic 64x64 transpose+cvt tile: dst[c0+t][r0+f] = src[r0+f][c0+t]
__device__ __forceinline__ void tcvt_tile(const float* __restrict__ src,
                                          f16* __restrict__ dst,
                                          int sstride, int dstride,
                                          int r0, int c0, int tid,
                                          float (*ld)[65]) {
    const int lrr = tid >> 4, lc = (tid & 15) * 4;
    const float4 v0 = *(const float4*)&src[(i64)(r0 + lrr + 0) * sstride + c0 + lc];
    const float4 v1 = *(const float4*)&src[(i64)(r0 + lrr + 16) * sstride + c0 + lc];
    const float4 v2 = *(const float4*)&src[(i64)(r0 + lrr + 32) * sstride + c0 + lc];
    const float4 v3 = *(const float4*)&src[(i64)(r0 + lrr + 48) * sstride + c0 + lc];
    ld[lrr + 0][lc + 0] = v0.x; ld[lrr + 0][lc + 1] = v0.y;
    ld[lrr + 0][lc + 2] = v0.z; ld[lrr + 0][lc + 3] = v0.w;
    ld[lrr + 16][lc + 0] = v1.x; ld[lrr + 16][lc + 1] = v1.y;
    ld[lrr + 16][lc + 2] = v1.z; ld[lrr + 16][lc + 3] = v1.w;
    ld[lrr + 32][lc + 0] = v2.x; ld[lrr + 32][lc + 1] = v2.y;
    ld[lrr + 32][lc + 2] = v2.z; ld[lrr + 32][lc + 3] = v2.w;
    ld[lrr + 48][lc + 0] = v3.x; ld[lrr + 48][lc + 1] = v3.y;
    ld[lrr + 48][lc + 2] = v3.z; ld[lrr + 48][lc + 3] = v3.w;
    __syncthreads();
    const int tr2 = tid >> 3, fc = (tid & 7) * 8;
#pragma unroll
    for (int pass = 0; pass < 2; ++pass) {
        const int t = tr2 + pass * 32;
        f16x8 o;
#pragma unroll
        for (int j = 0; j < 8; ++j) o[j] = (f16)ld[fc + j][t];
        *(f16x8*)&dst[(i64)(c0 + t) * dstride + r0 + fc] = o;
    }
}

// ================= prologue: x-tcvt || W1^T-tcvt || W2 cvt || zeros || beff ===
// bid<8192: x [f][t] f32 -> xh [t][f] f16 ; [8192,8256): W1 -> W1t f16 (transposed)
// [8256,8384): W2 -> W2h f16 ; 8384: zeros512 ; [8385,8387): beff = W2@b1+b2
__global__ __launch_bounds__(256) void k_pre2(const float* __restrict__ X,
                                              f16* __restrict__ O,
                                              const float* __restrict__ W1,
                                              f16* __restrict__ W1t,
                                              const float* __restrict__ W2,
                                              f16* __restrict__ W2h,
                                              float* __restrict__ zrs,
                                              const float* __restrict__ b1,
                                              const float* __restrict__ b2,
                                              float* __restrict__ beff) {
    __shared__ float ld[64][65];
    const int bid = blockIdx.x;
    const int tid = threadIdx.x;
    if (bid < 8192) {
        const int p = bid >> 5;
        const int f0 = ((bid >> 2) & 7) * 64, t0 = (bid & 3) * 64;
        tcvt_tile(X + (i64)p * PLANE, O + (i64)p * PLANE, TB, FB, f0, t0, tid, ld);
    } else if (bid < 8256) {
        const int w = bid - 8192;
        tcvt_tile(W1, W1t, FB, FB, (w >> 3) * 64, (w & 7) * 64, tid, ld);
    } else if (bid < 8384) {
        const i64 idx = ((i64)(bid - 8256) * 256 + tid) * 8;
        const float4 a = *(const float4*)&W2[idx];
        const float4 b = *(const float4*)&W2[idx + 4];
        f16x8 o;
        o[0] = (f16)a.x; o[1] = (f16)a.y; o[2] = (f16)a.z; o[3] = (f16)a.w;
        o[4] = (f16)b.x; o[5] = (f16)b.y; o[6] = (f16)b.z; o[7] = (f16)b.w;
        *(f16x8*)&W2h[idx] = o;
    } else if (bid == 8384) {
        zrs[tid] = 0.f;
        zrs[tid + 256] = 0.f;
    } else {
        const int m = (bid - 8385) * 256 + tid;
        const float* w2r = W2 + (i64)m * FB;
        float acc = b2[m];
#pragma unroll 4
        for (int k = 0; k < FB; ++k) acc = fmaf(w2r[k], b1[k], acc);
        beff[m] = acc;
    }
}

// ---------- real MFMA GEMM: Out[t][m] (f16) = sum_k A[m][k]*In[t][k] + bias[m]
// Also used for Weff = W2@W1: A=W1t, In=W2h, bias=0 -> Out[m][kk]=Weff.
__global__ __launch_bounds__(256, 2) void k_rgemm(const f16* __restrict__ A,
                                                  const f16* __restrict__ In,
                                                  const float* __restrict__ bias,
                                                  f16* __restrict__ Out) {
    __shared__ f16 Asx[128][40], Bsx[128][40];
    const int slab = blockIdx.z;
    const f16* Bsrc = In + (i64)slab * PLANE;
    f16* Odst = Out + (i64)slab * PLANE;
    const int t0 = blockIdx.x * 128, m0 = blockIdx.y * 128;
    const int tid = threadIdx.x;
    const int wave = tid >> 6, lane = tid & 63;
    const int wm = wave >> 1, wn = wave & 1;
    const int lr = lane & 15, lg = lane >> 4;
    const int srow = tid >> 2, sgrp = (tid & 3) * 8;

    f32x4 acc[4][4] = {};
    f16x8 nA[2], nB[2];
#pragma unroll
    for (int i = 0; i < 2; ++i) {
        const int row = i * 64 + srow;
        nA[i] = *(const f16x8*)(A + (i64)(m0 + row) * FB + sgrp);
        nB[i] = *(const f16x8*)(Bsrc + (i64)(t0 + row) * FB + sgrp);
    }
#pragma unroll
    for (int i = 0; i < 2; ++i) {
        const int row = i * 64 + srow;
        *(f16x8*)&Asx[row][sgrp] = nA[i];
        *(f16x8*)&Bsx[row][sgrp] = nB[i];
    }
    __syncthreads();

#pragma unroll 1
    for (int kt = 0; kt < 16; ++kt) {
        if (kt < 15) {
            const int k0 = (kt + 1) * 32;
#pragma unroll
            for (int i = 0; i < 2; ++i) {
                const int row = i * 64 + srow;
                nA[i] = *(const f16x8*)(A + (i64)(m0 + row) * FB + k0 + sgrp);
                nB[i] = *(const f16x8*)(Bsrc + (i64)(t0 + row) * FB + k0 + sgrp);
            }
        }
        f16x8 aA[4], bB[4];
#pragma unroll
        for (int mf = 0; mf < 4; ++mf)
            aA[mf] = *(const f16x8*)&Asx[wm * 64 + mf * 16 + lr][lg * 8];
#pragma unroll
        for (int nf = 0; nf < 4; ++nf)
            bB[nf] = *(const f16x8*)&Bsx[wn * 64 + nf * 16 + lr][lg * 8];
#pragma unroll
        for (int nf = 0; nf < 4; ++nf)
#pragma unroll
            for (int mf = 0; mf < 4; ++mf)
                acc[mf][nf] = MFMA16(aA[mf], bB[nf], acc[mf][nf]);
        __syncthreads();
        if (kt < 15) {
#pragma unroll
            for (int i = 0; i < 2; ++i) {
                const int row = i * 64 + srow;
                *(f16x8*)&Asx[row][sgrp] = nA[i];
                *(f16x8*)&Bsx[row][sgrp] = nB[i];
            }
        }
        __syncthreads();
    }

#pragma unroll
    for (int mf = 0; mf < 4; ++mf) {
        const int m = m0 + wm * 64 + mf * 16 + lg * 4;
        const float4 bv = *(const float4*)&bias[m];
        const float bb[4] = {bv.x, bv.y, bv.z, bv.w};
#pragma unroll
        for (int nf = 0; nf < 4; ++nf) {
            const int t = t0 + wn * 64 + nf * 16 + lr;
            f16x4 o;
#pragma unroll
            for (int r = 0; r < 4; ++r) o[r] = (f16)(acc[mf][nf][r] + bb[r]);
            *(f16x4*)&Odst[(i64)t * FB + m] = o;
        }
    }
}

// ================= fused softmax + conjFFT/mul/FFT, radix-8 three-step =======
// FFT arrangement: z[p] at (lane=p%64, reg=p/64). Global I/O contiguous
// (16B/lane); LDS marshal pre/post. All LDS phases conflict-free (r8-r9).

#define TWO_PI_OVER_512 0.012271846303085129f
#define TWO_PI_OVER_64 0.0981747704246810387f
#define R2C 0.70710678118654752f

template <int SGN>
__device__ __forceinline__ void fft8(float xr[8], float xi[8]) {
    const float sg = (float)SGN;   // W8 = e^{SGN*i*2pi/8}
    float t0r = xr[0] + xr[4], t0i = xi[0] + xi[4];
    float u0r = xr[0] - xr[4], u0i = xi[0] - xi[4];
    float t1r = xr[1] + xr[5], t1i = xi[1] + xi[5];
    float d1r = xr[1] - xr[5], d1i = xi[1] - xi[5];
    float u1r = R2C * (d1r - sg * d1i), u1i = R2C * (sg * d1r + d1i);
    float t2r = xr[2] + xr[6], t2i = xi[2] + xi[6];
    float d2r = xr[2] - xr[6], d2i = xi[2] - xi[6];
    float u2r = -sg * d2i, u2i = sg * d2r;
    float t3r = xr[3] + xr[7], t3i = xi[3] + xi[7];
    float d3r = xr[3] - xr[7], d3i = xi[3] - xi[7];
    float u3r = -R2C * (d3r + sg * d3i), u3i = R2C * (sg * d3r - d3i);
    float p0r = t0r + t2r, p0i = t0i + t2i, q0r = t0r - t2r, q0i = t0i - t2i;
    float p1r = t1r + t3r, p1i = t1i + t3i;
    float q1r = -sg * (t1i - t3i), q1i = sg * (t1r - t3r);
    float p2r = u0r + u2r, p2i = u0i + u2i, q2r = u0r - u2r, q2i = u0i - u2i;
    float p3r = u1r + u3r, p3i = u1i + u3i;
    float q3r = -sg * (u1i - u3i), q3i = sg * (u1r - u3r);
    xr[0] = p0r + p1r; xi[0] = p0i + p1i;
    xr[4] = p0r - p1r; xi[4] = p0i - p1i;
    xr[2] = q0r + q1r; xi[2] = q0i + q1i;
    xr[6] = q0r - q1r; xi[6] = q0i - q1i;
    xr[1] = p2r + p3r; xi[1] = p2i + p3i;
    xr[5] = p2r - p3r; xi[5] = p2i - p3i;
    xr[3] = q2r + q3r; xi[3] = q2i + q3i;
    xr[7] = q2r - q3r; xi[7] = q2i - q3i;
}

template <int SGN>
__device__ __forceinline__ void fft512x2(float ar[8], float ai[8],
                                         float br[8], float bi[8], int lane,
                                         float4* __restrict__ L,
                                         const float w1c[7], const float w1s[7],
                                         const float w2c[7], const float w2s[7]) {
    const float sg = (float)SGN;
    fft8<SGN>(ar, ai);
    fft8<SGN>(br, bi);
#pragma unroll
    for (int m = 1; m < 8; ++m) {
        const float wc = w1c[m - 1], ws = sg * w1s[m - 1];
        float tr = ar[m], ti = ai[m];
        ar[m] = tr * wc - ti * ws; ai[m] = tr * ws + ti * wc;
        tr = br[m]; ti = bi[m];
        br[m] = tr * wc - ti * ws; bi[m] = tr * ws + ti * wc;
    }
    // transpose 1: linear write lane*9+m ; permuted read (a8+8b8)*9+m8
#pragma unroll
    for (int m = 0; m < 8; ++m)
        L[lane * 9 + m] = make_float4(ar[m], ai[m], br[m], bi[m]);
    {
        const int a8 = lane & 7, m8 = lane >> 3;
#pragma unroll
        for (int b8 = 0; b8 < 8; ++b8) {
            const float4 v = L[(a8 + 8 * b8) * 9 + m8];
            ar[b8] = v.x; ai[b8] = v.y; br[b8] = v.z; bi[b8] = v.w;
        }
    }
    fft8<SGN>(ar, ai);
    fft8<SGN>(br, bi);
#pragma unroll
    for (int n = 1; n < 8; ++n) {
        const float wc = w2c[n - 1], ws = sg * w2s[n - 1];
        float tr = ar[n], ti = ai[n];
        ar[n] = tr * wc - ti * ws; ai[n] = tr * ws + ti * wc;
        tr = br[n]; ti = bi[n];
        br[n] = tr * wc - ti * ws; bi[n] = tr * ws + ti * wc;
    }
    // transpose 2: scatter write (m+8n)*9+a ; linear read lane*9+j
    {
        const int a2 = lane & 7, m2 = lane >> 3;
#pragma unroll
        for (int n = 0; n < 8; ++n)
            L[(m2 + 8 * n) * 9 + a2] = make_float4(ar[n], ai[n], br[n], bi[n]);
    }
#pragma unroll
    for (int j = 0; j < 8; ++j) {
        const float4 v = L[lane * 9 + j];
        ar[j] = v.x; ai[j] = v.y; br[j] = v.z; bi[j] = v.w;
    }
    fft8<SGN>(ar, ai);
    fft8<SGN>(br, bi);
}

__device__ __forceinline__ float wave_max(float v) {
#pragma unroll
    for (int m = 1; m <= 32; m <<= 1) v = fmaxf(v, __shfl_xor(v, m));
    return v;
}
__device__ __forceinline__ float wave_sum(float v) {
#pragma unroll
    for (int m = 1; m <= 32; m <<= 1) v += __shfl_xor(v, m);
    return v;
}

__device__ __forceinline__ void softmax8(float w[8]) {
    float mx = w[0];
#pragma unroll
    for (int j = 1; j < 8; ++j) mx = fmaxf(mx, w[j]);
    mx = wave_max(mx);
    float sm = 0.f;
#pragma unroll
    for (int j = 0; j < 8; ++j) { w[j] = __expf(w[j] - mx); sm += w[j]; }
    sm = wave_sum(sm);
    const float inv = 1.0f / sm;
#pragma unroll
    for (int j = 0; j < 8; ++j) w[j] *= inv;
}

__device__ __forceinline__ void load_marshal(const f16* __restrict__ Hre,
                                             const f16* __restrict__ Him,
                                             const f16* __restrict__ Wre,
                                             const f16* __restrict__ Wim,
                                             i64 rowbase, int lane,
                                             float4* __restrict__ L,
                                             float hr[8], float hi2[8],
                                             float wr[8], float wi[8]) {
    const f16x8 vhr = *(const f16x8*)(Hre + rowbase + 8 * lane);
    const f16x8 vhi = *(const f16x8*)(Him + rowbase + 8 * lane);
    const f16x8 vwr = *(const f16x8*)(Wre + rowbase + 8 * lane);
    const f16x8 vwi = *(const f16x8*)(Wim + rowbase + 8 * lane);
#pragma unroll
    for (int j = 0; j < 8; ++j)
        L[lane * 9 + j] = make_float4((float)vhr[j], (float)vhi[j],
                                      (float)vwr[j], (float)vwi[j]);
    const int c = lane >> 3, q = lane & 7;
#pragma unroll
    for (int v = 0; v < 8; ++v) {
        const float4 f4 = L[(8 * v + c) * 9 + q];
        hr[v] = f4.x; hi2[v] = f4.y; wr[v] = f4.z; wi[v] = f4.w;
    }
}

__device__ __forceinline__ void fftconv_block(const f16* __restrict__ xh,
                                              const f16* __restrict__ logits,
                                              float* __restrict__ conv,
                                              int tblk, int cs, int chunkoff,
                                              int wave, int lane, float4* L) {
    const int b = cs >> 4, d = cs & 15;
    const int pre = b * 32 + d;
    const int pim = pre + 16;

    float w1c[7], w1s[7], w2c[7], w2s[7];
    {
        float s1, c1;
        __sincosf((float)lane * TWO_PI_OVER_512, &s1, &c1);
        w1c[0] = c1; w1s[0] = s1;
#pragma unroll
        for (int m = 1; m < 7; ++m) {
            const float pc = w1c[m - 1], ps = w1s[m - 1];
            w1c[m] = pc * c1 - ps * s1;
            w1s[m] = pc * s1 + ps * c1;
        }
        float s2, c2;
        __sincosf((float)(lane & 7) * TWO_PI_OVER_64, &s2, &c2);
        w2c[0] = c2; w2s[0] = s2;
#pragma unroll
        for (int n = 1; n < 7; ++n) {
            const float pc = w2c[n - 1], ps = w2s[n - 1];
            w2c[n] = pc * c2 - ps * s2;
            w2s[n] = pc * s2 + ps * c2;
        }
    }

    const f16* Hre = xh + (i64)pre * PLANE;
    const f16* Him = xh + (i64)pim * PLANE;
    const f16* Wre = logits + (i64)pre * PLANE;
    const f16* Wim = logits + (i64)pim * PLANE;
    float* Cre = conv + (i64)(pre - chunkoff) * PLANE;
    float* Cim = conv + (i64)(pim - chunkoff) * PLANE;

    const int t1a = tblk * 8 + wave * 2;

    float p0r[8], p0i[8], p1r[8], p1i[8];
    {
        float hr[8], hi2[8], wr[8], wi[8];
        load_marshal(Hre, Him, Wre, Wim, (i64)t1a * FB, lane, L, hr, hi2, wr, wi);
        softmax8(wr);
        softmax8(wi);
        fft512x2<1>(hr, hi2, wr, wi, lane, L, w1c, w1s, w2c, w2s);
#pragma unroll
        for (int j = 0; j < 8; ++j) {
            p0r[j] = (hr[j] * wr[j] - hi2[j] * wi[j]) * (1.0f / 512.0f);
            p0i[j] = (hr[j] * wi[j] + hi2[j] * wr[j]) * (1.0f / 512.0f);
        }
    }
    {
        float hr[8], hi2[8], wr[8], wi[8];
        load_marshal(Hre, Him, Wre, Wim, (i64)(t1a + 1) * FB, lane, L, hr, hi2, wr, wi);
        softmax8(wr);
        softmax8(wi);
        fft512x2<1>(hr, hi2, wr, wi, lane, L, w1c, w1s, w2c, w2s);
#pragma unroll
        for (int j = 0; j < 8; ++j) {
            p1r[j] = (hr[j] * wr[j] - hi2[j] * wi[j]) * (1.0f / 512.0f);
            p1i[j] = (hr[j] * wi[j] + hi2[j] * wr[j]) * (1.0f / 512.0f);
        }
    }
    fft512x2<-1>(p0r, p0i, p1r, p1i, lane, L, w1c, w1s, w2c, w2s);

    // post-transpose -> contiguous 16B/lane stores
    {
        const int a = lane & 7, bq = lane >> 3;
#pragma unroll
        for (int s = 0; s < 8; ++s)
            L[(bq + 8 * s) * 9 + a] = make_float4(p0r[s], p0i[s], p1r[s], p1i[s]);
    }
    float4 g[8];
#pragma unroll
    for (int j = 0; j < 8; ++j) g[j] = L[lane * 9 + j];
    float* C0r = Cre + (i64)t1a * FB + 8 * lane;
    float* C0i = Cim + (i64)t1a * FB + 8 * lane;
    float* C1r = Cre + (i64)(t1a + 1) * FB + 8 * lane;
    float* C1i = Cim + (i64)(t1a + 1) * FB + 8 * lane;
    *(float4*)(C0r + 0) = make_float4(g[0].x, g[1].x, g[2].x, g[3].x);
    *(float4*)(C0r + 4) = make_float4(g[4].x, g[5].x, g[6].x, g[7].x);
    *(float4*)(C0i + 0) = make_float4(g[0].y, g[1].y, g[2].y, g[3].y);
    *(float4*)(C0i + 4) = make_float4(g[4].y, g[5].y, g[6].y, g[7].y);
    *(float4*)(C1r + 0) = make_float4(g[0].z, g[1].z, g[2].z, g[3].z);
    *(float4*)(C1r + 4) = make_float4(g[4].z, g[5].z, g[6].z, g[7].z);
    *(float4*)(C1i + 0) = make_float4(g[0].w, g[1].w, g[2].w, g[3].w);
    *(float4*)(C1i + 4) = make_float4(g[4].w, g[5].w, g[6].w, g[7].w);
}

// transpose_out body: f32 [t][f] chunk plane p -> f32 [f][t] out plane p+pbase
__device__ __forceinline__ void transpose_block(const float* __restrict__ C,
                                                float* __restrict__ O,
                                                int tb, int fb, int p, int pbase,
                                                int tid, float (*ld)[65]) {
    const float* src = C + (i64)p * PLANE;
    float* dst = O + (i64)(p + pbase) * PLANE;
    const int t0 = tb * 64, f0 = fb * 64;
    const int lrr = tid >> 4, lc = (tid & 15) * 4;
#pragma unroll
    for (int i = 0; i < 4; ++i) {
        float4 v = *(const float4*)&src[(i64)(t0 + lrr + i * 16) * FB + f0 + lc];
        ld[lc + 0][lrr + i * 16] = v.x;
        ld[lc + 1][lrr + i * 16] = v.y;
        ld[lc + 2][lrr + i * 16] = v.z;
        ld[lc + 3][lrr + i * 16] = v.w;
    }
    __syncthreads();
    const int fr = tid >> 4, tc = (tid & 15) * 4;
#pragma unroll
    for (int i = 0; i < 4; ++i) {
        const int f = fr + i * 16;
        float4 o;
        o.x = ld[f][tc + 0]; o.y = ld[f][tc + 1];
        o.z = ld[f][tc + 2]; o.w = ld[f][tc + 3];
        *(float4*)&dst[(i64)(f0 + f) * TB + t0 + tc] = o;
    }
}

// ---------- fftconv launcher (csbase/chunkoff parametric)
__global__ __launch_bounds__(256, 2) void k_fftconv(const f16* __restrict__ xh,
                                                    const f16* __restrict__ logits,
                                                    float* __restrict__ conv,
                                                    int csbase, int chunkoff) {
    __shared__ float4 LDS[4][576];
    const int wave = threadIdx.x >> 6, lane = threadIdx.x & 63;
    fftconv_block(xh, logits, conv, blockIdx.x, blockIdx.y + csbase, chunkoff,
                  wave, lane, LDS[wave]);
}

// ---------- role-split mid: fftconv(pairs 64..127 -> conv1) || transpose(conv0 -> out)
__global__ __launch_bounds__(256, 2) void k_mid(const f16* __restrict__ xh,
                                                const f16* __restrict__ logits,
                                                float* __restrict__ conv1,
                                                const float* __restrict__ conv0,
                                                float* __restrict__ out) {
    __shared__ __align__(16) char raw[36864];
    const int bid = blockIdx.x;
    const int tid = threadIdx.x;
    if (bid < 2048) {
        const int wave = tid >> 6, lane = tid & 63;
        float4* L = (float4*)raw + wave * 576;
        fftconv_block(xh, logits, conv1, bid & 31, 64 + (bid >> 5), 128, wave, lane, L);
    } else {
        const int w = bid - 2048;
        float (*ld)[65] = (float(*)[65])raw;
        transpose_block(conv0, out, w & 3, (w >> 2) & 7, w >> 5, 0, tid, ld);
    }
}

// ---------- final transpose
__global__ __launch_bounds__(256) void k_transpose_out(const float* __restrict__ C,
                                                       float* __restrict__ O,
                                                       int pbase) {
    __shared__ float ld[64][65];
    transpose_block(C, O, blockIdx.x, blockIdx.y, blockIdx.z, pbase, threadIdx.x, ld);
}

extern "C" void kernel_launch(void* const* d_in, const int* in_sizes, int n_in,
                              void* d_out, int out_size, void* d_ws, size_t ws_size,
                              hipStream_t stream) {
    (void)in_sizes; (void)n_in; (void)out_size;
    const float* x = (const float*)d_in[0];
    const float* W1 = (const float*)d_in[1];
    const float* b1 = (const float*)d_in[2];
    const float* W2 = (const float*)d_in[3];
    const float* b2 = (const float*)d_in[4];
    float* out = (float*)d_out;

    char* ws = (char*)d_ws;
    const i64 TENB = (i64)67108864;                       // f16 tensor / f32 half-tensor bytes
    f16* Weff  = (f16*)(ws);                              // 512 KB
    float* beff = (float*)(ws + 524288);                  // 2 KB (pad to 4 KB)
    f16* W1t  = (f16*)(ws + 528384);                      // 512 KB
    f16* W2h  = (f16*)(ws + 1052672);                     // 512 KB
    float* zrs = (float*)(ws + 1576960);                  // 2 KB (pad to 4 KB)
    f16* xh     = (f16*)(ws + 1581056);                   // 67.1 MB
    f16* logits = (f16*)(ws + 1581056 + TENB);            // 67.1 MB
    float* conv0 = (float*)(ws + 1581056 + 2 * TENB);     // 67.1 MB
    float* conv1 = (float*)(ws + 1581056 + 3 * TENB);     // 67.1 MB

    // L1: x-tcvt || W1^T-tcvt || W2-cvt || zeros || beff
    k_pre2<<<dim3(8387), dim3(256), 0, stream>>>(x, xh, W1, W1t, W2, W2h, zrs, b1, b2, beff);
    // L2: Weff = W2 @ W1 via MFMA (Out[m][kk], 16 blocks)
    k_rgemm<<<dim3(4, 4, 1), dim3(256), 0, stream>>>(W1t, W2h, zrs, Weff);
    // L3: logits = Weff @ X + beff
    k_rgemm<<<dim3(TB / 128, FB / 128, 256), dim3(256), 0, stream>>>(Weff, xh, beff, logits);

    const size_t need_dual = (size_t)1581056 + 4 * (size_t)TENB;
    if (ws_size >= need_dual) {
        // L4: chunk-0 fftconv -> conv0
        k_fftconv<<<dim3(32, 64), dim3(256), 0, stream>>>(xh, logits, conv0, 0, 0);
        // L5: chunk-1 fftconv -> conv1 || transpose conv0 -> out[0:128]
        k_mid<<<dim3(6144), dim3(256), 0, stream>>>(xh, logits, conv1, conv0, out);
        // L6: transpose conv1 -> out[128:256]
        k_transpose_out<<<dim3(4, 8, 128), dim3(256), 0, stream>>>(conv1, out, 128);
    } else {
        // serial fallback within one conv buffer
        k_fftconv<<<dim3(32, 64), dim3(256), 0, stream>>>(xh, logits, conv0, 0, 0);
        k_transpose_out<<<dim3(4, 8, 128), dim3(256), 0, stream>>>(conv0, out, 0);
        k_fftconv<<<dim3(32, 64), dim3(256), 0, stream>>>(xh, logits, conv0, 64, 128);
        k_transpose_out<<<dim3(4, 8, 128), dim3(256), 0, stream>>>(conv0, out, 128);
    }
}

// Round 12
// 245.218 us; speedup vs baseline: 1.1743x; 1.0652x over previous
//
#include <hip/hip_runtime.h>
#include <math.h>

#define FB 512
#define TB 256
#define PLANE (FB * TB)
typedef long long i64;
typedef _Float16 f16;
typedef _Float16 f16x8 __attribute__((ext_vector_type(8)));
typedef _Float16 f16x4 __attribute__((ext_vector_type(4)));
typedef float f32x4 __attribute__((ext_vector_type(4)));

#define MFMA16(a, b, c) __builtin_amdgcn_mfma_f32_16x16x32_f16(a, b, c, 0, 0, 0)

// ---------- generic 64x64 transpose+cvt tile: dst[c0+t][r0+f] = src[r0+f][c0+t]
// asm fence keeps all 4 loads live -> issued back-to-back (r11: VGPR=16 had
// serialized them; VALUBusy 2.2% at 81us).
__device__ __forceinline__ void tcvt_tile(const float* __restrict__ src,
                                          f16* __restrict__ dst,
                                          int sstride, int dstride,
                                          int r0, int c0, int tid,
                                          float (*ld)[65]) {
    const int lrr = tid >> 4, lc = (tid & 15) * 4;
    f32x4 v0 = *(const f32x4*)&src[(i64)(r0 + lrr + 0) * sstride + c0 + lc];
    f32x4 v1 = *(const f32x4*)&src[(i64)(r0 + lrr + 16) * sstride + c0 + lc];
    f32x4 v2 = *(const f32x4*)&src[(i64)(r0 + lrr + 32) * sstride + c0 + lc];
    f32x4 v3 = *(const f32x4*)&src[(i64)(r0 + lrr + 48) * sstride + c0 + lc];
    asm volatile("" : "+v"(v0), "+v"(v1), "+v"(v2), "+v"(v3));
#pragma unroll
    for (int j = 0; j < 4; ++j) {
        ld[lrr + 0][lc + j] = v0[j];
        ld[lrr + 16][lc + j] = v1[j];
        ld[lrr + 32][lc + j] = v2[j];
        ld[lrr + 48][lc + j] = v3[j];
    }
    __syncthreads();
    const int tr2 = tid >> 3, fc = (tid & 7) * 8;
#pragma unroll
    for (int pass = 0; pass < 2; ++pass) {
        const int t = tr2 + pass * 32;
        f16x8 o;
#pragma unroll
        for (int j = 0; j < 8; ++j) o[j] = (f16)ld[fc + j][t];
        *(f16x8*)&dst[(i64)(c0 + t) * dstride + r0 + fc] = o;
    }
}

// ================= prologue: x-tcvt || W1^T-tcvt || W2 cvt || zeros || beff ===
__global__ __launch_bounds__(256) void k_pre2(const float* __restrict__ X,
                                              f16* __restrict__ O,
                                              const float* __restrict__ W1,
                                              f16* __restrict__ W1t,
                                              const float* __restrict__ W2,
                                              f16* __restrict__ W2h,
                                              float* __restrict__ zrs,
                                              const float* __restrict__ b1,
                                              const float* __restrict__ b2,
                                              float* __restrict__ beff) {
    __shared__ float ld[64][65];
    const int bid = blockIdx.x;
    const int tid = threadIdx.x;
    if (bid < 8192) {
        const int p = bid >> 5;
        const int f0 = ((bid >> 2) & 7) * 64, t0 = (bid & 3) * 64;
        tcvt_tile(X + (i64)p * PLANE, O + (i64)p * PLANE, TB, FB, f0, t0, tid, ld);
    } else if (bid < 8256) {
        const int w = bid - 8192;
        tcvt_tile(W1, W1t, FB, FB, (w >> 3) * 64, (w & 7) * 64, tid, ld);
    } else if (bid < 8384) {
        const i64 idx = ((i64)(bid - 8256) * 256 + tid) * 8;
        const float4 a = *(const float4*)&W2[idx];
        const float4 b = *(const float4*)&W2[idx + 4];
        f16x8 o;
        o[0] = (f16)a.x; o[1] = (f16)a.y; o[2] = (f16)a.z; o[3] = (f16)a.w;
        o[4] = (f16)b.x; o[5] = (f16)b.y; o[6] = (f16)b.z; o[7] = (f16)b.w;
        *(f16x8*)&W2h[idx] = o;
    } else if (bid == 8384) {
        zrs[tid] = 0.f;
        zrs[tid + 256] = 0.f;
    } else {
        const int m = (bid - 8385) * 256 + tid;
        const float* w2r = W2 + (i64)m * FB;
        float acc = b2[m];
#pragma unroll 4
        for (int k = 0; k < FB; ++k) acc = fmaf(w2r[k], b1[k], acc);
        beff[m] = acc;
    }
}

// ---------- real MFMA GEMM: Out[t][m] (f16) = sum_k A[m][k]*In[t][k] + bias[m]
// Also used for Weff = W2@W1: A=W1t, In=W2h, bias=0 -> Out[m][kk]=Weff.
__global__ __launch_bounds__(256, 2) void k_rgemm(const f16* __restrict__ A,
                                                  const f16* __restrict__ In,
                                                  const float* __restrict__ bias,
                                                  f16* __restrict__ Out) {
    __shared__ f16 Asx[128][40], Bsx[128][40];
    const int slab = blockIdx.z;
    const f16* Bsrc = In + (i64)slab * PLANE;
    f16* Odst = Out + (i64)slab * PLANE;
    const int t0 = blockIdx.x * 128, m0 = blockIdx.y * 128;
    const int tid = threadIdx.x;
    const int wave = tid >> 6, lane = tid & 63;
    const int wm = wave >> 1, wn = wave & 1;
    const int lr = lane & 15, lg = lane >> 4;
    const int srow = tid >> 2, sgrp = (tid & 3) * 8;

    f32x4 acc[4][4] = {};
    f16x8 nA[2], nB[2];
#pragma unroll
    for (int i = 0; i < 2; ++i) {
        const int row = i * 64 + srow;
        nA[i] = *(const f16x8*)(A + (i64)(m0 + row) * FB + sgrp);
        nB[i] = *(const f16x8*)(Bsrc + (i64)(t0 + row) * FB + sgrp);
    }
#pragma unroll
    for (int i = 0; i < 2; ++i) {
        const int row = i * 64 + srow;
        *(f16x8*)&Asx[row][sgrp] = nA[i];
        *(f16x8*)&Bsx[row][sgrp] = nB[i];
    }
    __syncthreads();

#pragma unroll 1
    for (int kt = 0; kt < 16; ++kt) {
        if (kt < 15) {
            const int k0 = (kt + 1) * 32;
#pragma unroll
            for (int i = 0; i < 2; ++i) {
                const int row = i * 64 + srow;
                nA[i] = *(const f16x8*)(A + (i64)(m0 + row) * FB + k0 + sgrp);
                nB[i] = *(const f16x8*)(Bsrc + (i64)(t0 + row) * FB + k0 + sgrp);
            }
        }
        f16x8 aA[4], bB[4];
#pragma unroll
        for (int mf = 0; mf < 4; ++mf)
            aA[mf] = *(const f16x8*)&Asx[wm * 64 + mf * 16 + lr][lg * 8];
#pragma unroll
        for (int nf = 0; nf < 4; ++nf)
            bB[nf] = *(const f16x8*)&Bsx[wn * 64 + nf * 16 + lr][lg * 8];
#pragma unroll
        for (int nf = 0; nf < 4; ++nf)
#pragma unroll
            for (int mf = 0; mf < 4; ++mf)
                acc[mf][nf] = MFMA16(aA[mf], bB[nf], acc[mf][nf]);
        __syncthreads();
        if (kt < 15) {
#pragma unroll
            for (int i = 0; i < 2; ++i) {
                const int row = i * 64 + srow;
                *(f16x8*)&Asx[row][sgrp] = nA[i];
                *(f16x8*)&Bsx[row][sgrp] = nB[i];
            }
        }
        __syncthreads();
    }

#pragma unroll
    for (int mf = 0; mf < 4; ++mf) {
        const int m = m0 + wm * 64 + mf * 16 + lg * 4;
        const float4 bv = *(const float4*)&bias[m];
        const float bb[4] = {bv.x, bv.y, bv.z, bv.w};
#pragma unroll
        for (int nf = 0; nf < 4; ++nf) {
            const int t = t0 + wn * 64 + nf * 16 + lr;
            f16x4 o;
#pragma unroll
            for (int r = 0; r < 4; ++r) o[r] = (f16)(acc[mf][nf][r] + bb[r]);
            *(f16x4*)&Odst[(i64)t * FB + m] = o;
        }
    }
}

// ================= fused softmax + conjFFT/mul/FFT, radix-8 three-step =======
// FFT arrangement: z[p] at (lane=p%64, reg=p/64). Global I/O contiguous
// (16B/lane); LDS marshal pre/post, conflict-free (r8-r9). Conv out = f16.

#define TWO_PI_OVER_512 0.012271846303085129f
#define TWO_PI_OVER_64 0.0981747704246810387f
#define R2C 0.70710678118654752f

template <int SGN>
__device__ __forceinline__ void fft8(float xr[8], float xi[8]) {
    const float sg = (float)SGN;   // W8 = e^{SGN*i*2pi/8}
    float t0r = xr[0] + xr[4], t0i = xi[0] + xi[4];
    float u0r = xr[0] - xr[4], u0i = xi[0] - xi[4];
    float t1r = xr[1] + xr[5], t1i = xi[1] + xi[5];
    float d1r = xr[1] - xr[5], d1i = xi[1] - xi[5];
    float u1r = R2C * (d1r - sg * d1i), u1i = R2C * (sg * d1r + d1i);
    float t2r = xr[2] + xr[6], t2i = xi[2] + xi[6];
    float d2r = xr[2] - xr[6], d2i = xi[2] - xi[6];
    float u2r = -sg * d2i, u2i = sg * d2r;
    float t3r = xr[3] + xr[7], t3i = xi[3] + xi[7];
    float d3r = xr[3] - xr[7], d3i = xi[3] - xi[7];
    float u3r = -R2C * (d3r + sg * d3i), u3i = R2C * (sg * d3r - d3i);
    float p0r = t0r + t2r, p0i = t0i + t2i, q0r = t0r - t2r, q0i = t0i - t2i;
    float p1r = t1r + t3r, p1i = t1i + t3i;
    float q1r = -sg * (t1i - t3i), q1i = sg * (t1r - t3r);
    float p2r = u0r + u2r, p2i = u0i + u2i, q2r = u0r - u2r, q2i = u0i - u2i;
    float p3r = u1r + u3r, p3i = u1i + u3i;
    float q3r = -sg * (u1i - u3i), q3i = sg * (u1r - u3r);
    xr[0] = p0r + p1r; xi[0] = p0i + p1i;
    xr[4] = p0r - p1r; xi[4] = p0i - p1i;
    xr[2] = q0r + q1r; xi[2] = q0i + q1i;
    xr[6] = q0r - q1r; xi[6] = q0i - q1i;
    xr[1] = p2r + p3r; xi[1] = p2i + p3i;
    xr[5] = p2r - p3r; xi[5] = p2i - p3i;
    xr[3] = q2r + q3r; xi[3] = q2i + q3i;
    xr[7] = q2r - q3r; xi[7] = q2i - q3i;
}

template <int SGN>
__device__ __forceinline__ void fft512x2(float ar[8], float ai[8],
                                         float br[8], float bi[8], int lane,
                                         float4* __restrict__ L,
                                         const float w1c[7], const float w1s[7],
                                         const float w2c[7], const float w2s[7]) {
    const float sg = (float)SGN;
    fft8<SGN>(ar, ai);
    fft8<SGN>(br, bi);
#pragma unroll
    for (int m = 1; m < 8; ++m) {
        const float wc = w1c[m - 1], ws = sg * w1s[m - 1];
        float tr = ar[m], ti = ai[m];
        ar[m] = tr * wc - ti * ws; ai[m] = tr * ws + ti * wc;
        tr = br[m]; ti = bi[m];
        br[m] = tr * wc - ti * ws; bi[m] = tr * ws + ti * wc;
    }
    // transpose 1: linear write lane*9+m ; permuted read (a8+8b8)*9+m8
#pragma unroll
    for (int m = 0; m < 8; ++m)
        L[lane * 9 + m] = make_float4(ar[m], ai[m], br[m], bi[m]);
    {
        const int a8 = lane & 7, m8 = lane >> 3;
#pragma unroll
        for (int b8 = 0; b8 < 8; ++b8) {
            const float4 v = L[(a8 + 8 * b8) * 9 + m8];
            ar[b8] = v.x; ai[b8] = v.y; br[b8] = v.z; bi[b8] = v.w;
        }
    }
    fft8<SGN>(ar, ai);
    fft8<SGN>(br, bi);
#pragma unroll
    for (int n = 1; n < 8; ++n) {
        const float wc = w2c[n - 1], ws = sg * w2s[n - 1];
        float tr = ar[n], ti = ai[n];
        ar[n] = tr * wc - ti * ws; ai[n] = tr * ws + ti * wc;
        tr = br[n]; ti = bi[n];
        br[n] = tr * wc - ti * ws; bi[n] = tr * ws + ti * wc;
    }
    // transpose 2: scatter write (m+8n)*9+a ; linear read lane*9+j
    {
        const int a2 = lane & 7, m2 = lane >> 3;
#pragma unroll
        for (int n = 0; n < 8; ++n)
            L[(m2 + 8 * n) * 9 + a2] = make_float4(ar[n], ai[n], br[n], bi[n]);
    }
#pragma unroll
    for (int j = 0; j < 8; ++j) {
        const float4 v = L[lane * 9 + j];
        ar[j] = v.x; ai[j] = v.y; br[j] = v.z; bi[j] = v.w;
    }
    fft8<SGN>(ar, ai);
    fft8<SGN>(br, bi);
}

__device__ __forceinline__ float wave_max(float v) {
#pragma unroll
    for (int m = 1; m <= 32; m <<= 1) v = fmaxf(v, __shfl_xor(v, m));
    return v;
}
__device__ __forceinline__ float wave_sum(float v) {
#pragma unroll
    for (int m = 1; m <= 32; m <<= 1) v += __shfl_xor(v, m);
    return v;
}

__device__ __forceinline__ void softmax8(float w[8]) {
    float mx = w[0];
#pragma unroll
    for (int j = 1; j < 8; ++j) mx = fmaxf(mx, w[j]);
    mx = wave_max(mx);
    float sm = 0.f;
#pragma unroll
    for (int j = 0; j < 8; ++j) { w[j] = __expf(w[j] - mx); sm += w[j]; }
    sm = wave_sum(sm);
    const float inv = 1.0f / sm;
#pragma unroll
    for (int j = 0; j < 8; ++j) w[j] *= inv;
}

__device__ __forceinline__ void load_marshal(const f16* __restrict__ Hre,
                                             const f16* __restrict__ Him,
                                             const f16* __restrict__ Wre,
                                             const f16* __restrict__ Wim,
                                             i64 rowbase, int lane,
                                             float4* __restrict__ L,
                                             float hr[8], float hi2[8],
                                             float wr[8], float wi[8]) {
    const f16x8 vhr = *(const f16x8*)(Hre + rowbase + 8 * lane);
    const f16x8 vhi = *(const f16x8*)(Him + rowbase + 8 * lane);
    const f16x8 vwr = *(const f16x8*)(Wre + rowbase + 8 * lane);
    const f16x8 vwi = *(const f16x8*)(Wim + rowbase + 8 * lane);
#pragma unroll
    for (int j = 0; j < 8; ++j)
        L[lane * 9 + j] = make_float4((float)vhr[j], (float)vhi[j],
                                      (float)vwr[j], (float)vwi[j]);
    const int c = lane >> 3, q = lane & 7;
#pragma unroll
    for (int v = 0; v < 8; ++v) {
        const float4 f4 = L[(8 * v + c) * 9 + q];
        hr[v] = f4.x; hi2[v] = f4.y; wr[v] = f4.z; wi[v] = f4.w;
    }
}

__device__ __forceinline__ void fftconv_block(const f16* __restrict__ xh,
                                              const f16* __restrict__ logits,
                                              f16* __restrict__ conv,
                                              int tblk, int cs, int chunkoff,
                                              int wave, int lane, float4* L) {
    const int b = cs >> 4, d = cs & 15;
    const int pre = b * 32 + d;
    const int pim = pre + 16;

    float w1c[7], w1s[7], w2c[7], w2s[7];
    {
        float s1, c1;
        __sincosf((float)lane * TWO_PI_OVER_512, &s1, &c1);
        w1c[0] = c1; w1s[0] = s1;
#pragma unroll
        for (int m = 1; m < 7; ++m) {
            const float pc = w1c[m - 1], ps = w1s[m - 1];
            w1c[m] = pc * c1 - ps * s1;
            w1s[m] = pc * s1 + ps * c1;
        }
        float s2, c2;
        __sincosf((float)(lane & 7) * TWO_PI_OVER_64, &s2, &c2);
        w2c[0] = c2; w2s[0] = s2;
#pragma unroll
        for (int n = 1; n < 7; ++n) {
            const float pc = w2c[n - 1], ps = w2s[n - 1];
            w2c[n] = pc * c2 - ps * s2;
            w2s[n] = pc * s2 + ps * c2;
        }
    }

    const f16* Hre = xh + (i64)pre * PLANE;
    const f16* Him = xh + (i64)pim * PLANE;
    const f16* Wre = logits + (i64)pre * PLANE;
    const f16* Wim = logits + (i64)pim * PLANE;
    f16* Cre = conv + (i64)(pre - chunkoff) * PLANE;
    f16* Cim = conv + (i64)(pim - chunkoff) * PLANE;

    const int t1a = tblk * 8 + wave * 2;

    float p0r[8], p0i[8], p1r[8], p1i[8];
    {
        float hr[8], hi2[8], wr[8], wi[8];
        load_marshal(Hre, Him, Wre, Wim, (i64)t1a * FB, lane, L, hr, hi2, wr, wi);
        softmax8(wr);
        softmax8(wi);
        fft512x2<1>(hr, hi2, wr, wi, lane, L, w1c, w1s, w2c, w2s);
#pragma unroll
        for (int j = 0; j < 8; ++j) {
            p0r[j] = (hr[j] * wr[j] - hi2[j] * wi[j]) * (1.0f / 512.0f);
            p0i[j] = (hr[j] * wi[j] + hi2[j] * wr[j]) * (1.0f / 512.0f);
        }
    }
    {
        float hr[8], hi2[8], wr[8], wi[8];
        load_marshal(Hre, Him, Wre, Wim, (i64)(t1a + 1) * FB, lane, L, hr, hi2, wr, wi);
        softmax8(wr);
        softmax8(wi);
        fft512x2<1>(hr, hi2, wr, wi, lane, L, w1c, w1s, w2c, w2s);
#pragma unroll
        for (int j = 0; j < 8; ++j) {
            p1r[j] = (hr[j] * wr[j] - hi2[j] * wi[j]) * (1.0f / 512.0f);
            p1i[j] = (hr[j] * wi[j] + hi2[j] * wr[j]) * (1.0f / 512.0f);
        }
    }
    fft512x2<-1>(p0r, p0i, p1r, p1i, lane, L, w1c, w1s, w2c, w2s);

    // post-transpose -> contiguous f16x8 (16B/lane) stores
    {
        const int a = lane & 7, bq = lane >> 3;
#pragma unroll
        for (int s = 0; s < 8; ++s)
            L[(bq + 8 * s) * 9 + a] = make_float4(p0r[s], p0i[s], p1r[s], p1i[s]);
    }
    f16x8 o0r, o0i, o1r, o1i;
#pragma unroll
    for (int j = 0; j < 8; ++j) {
        const float4 g = L[lane * 9 + j];
        o0r[j] = (f16)g.x; o0i[j] = (f16)g.y;
        o1r[j] = (f16)g.z; o1i[j] = (f16)g.w;
    }
    *(f16x8*)(Cre + (i64)t1a * FB + 8 * lane) = o0r;
    *(f16x8*)(Cim + (i64)t1a * FB + 8 * lane) = o0i;
    *(f16x8*)(Cre + (i64)(t1a + 1) * FB + 8 * lane) = o1r;
    *(f16x8*)(Cim + (i64)(t1a + 1) * FB + 8 * lane) = o1i;
}

// transpose_out body: f16 [t][f] chunk plane p -> f32 [f][t] out plane p+pbase
__device__ __forceinline__ void transpose_block(const f16* __restrict__ C,
                                                float* __restrict__ O,
                                                int tb, int fb, int p, int pbase,
                                                int tid, float (*ld)[65]) {
    const f16* src = C + (i64)p * PLANE;
    float* dst = O + (i64)(p + pbase) * PLANE;
    const int t0 = tb * 64, f0 = fb * 64;
    const int tr = tid >> 3, fc = (tid & 7) * 8;
    f16x8 u0 = *(const f16x8*)&src[(i64)(t0 + tr) * FB + f0 + fc];
    f16x8 u1 = *(const f16x8*)&src[(i64)(t0 + tr + 32) * FB + f0 + fc];
    asm volatile("" : "+v"(u0), "+v"(u1));
#pragma unroll
    for (int j = 0; j < 8; ++j) {
        ld[fc + j][tr] = (float)u0[j];
        ld[fc + j][tr + 32] = (float)u1[j];
    }
    __syncthreads();
    const int fr = tid >> 4, tc = (tid & 15) * 4;
#pragma unroll
    for (int i = 0; i < 4; ++i) {
        const int f = fr + i * 16;
        float4 o;
        o.x = ld[f][tc + 0]; o.y = ld[f][tc + 1];
        o.z = ld[f][tc + 2]; o.w = ld[f][tc + 3];
        *(float4*)&dst[(i64)(f0 + f) * TB + t0 + tc] = o;
    }
}

// ---------- fftconv launcher (csbase/chunkoff parametric)
__global__ __launch_bounds__(256, 2) void k_fftconv(const f16* __restrict__ xh,
                                                    const f16* __restrict__ logits,
                                                    f16* __restrict__ conv,
                                                    int csbase, int chunkoff) {
    __shared__ float4 LDS[4][576];
    const int wave = threadIdx.x >> 6, lane = threadIdx.x & 63;
    fftconv_block(xh, logits, conv, blockIdx.x, blockIdx.y + csbase, chunkoff,
                  wave, lane, LDS[wave]);
}

// ---------- role-split mid: fftconv(pairs 64..127 -> conv1) || transpose(conv0 -> out)
__global__ __launch_bounds__(256, 2) void k_mid(const f16* __restrict__ xh,
                                                const f16* __restrict__ logits,
                                                f16* __restrict__ conv1,
                                                const f16* __restrict__ conv0,
                                                float* __restrict__ out) {
    __shared__ __align__(16) char raw[36864];
    const int bid = blockIdx.x;
    const int tid = threadIdx.x;
    if (bid < 2048) {
        const int wave = tid >> 6, lane = tid & 63;
        float4* L = (float4*)raw + wave * 576;
        fftconv_block(xh, logits, conv1, bid & 31, 64 + (bid >> 5), 128, wave, lane, L);
    } else {
        const int w = bid - 2048;
        float (*ld)[65] = (float(*)[65])raw;
        transpose_block(conv0, out, w & 3, (w >> 2) & 7, w >> 5, 0, tid, ld);
    }
}

// ---------- final transpose
__global__ __launch_bounds__(256) void k_transpose_out(const f16* __restrict__ C,
                                                       float* __restrict__ O,
                                                       int pbase) {
    __shared__ float ld[64][65];
    transpose_block(C, O, blockIdx.x, blockIdx.y, blockIdx.z, pbase, threadIdx.x, ld);
}

extern "C" void kernel_launch(void* const* d_in, const int* in_sizes, int n_in,
                              void* d_out, int out_size, void* d_ws, size_t ws_size,
                              hipStream_t stream) {
    (void)in_sizes; (void)n_in; (void)out_size; (void)ws_size;
    const float* x = (const float*)d_in[0];
    const float* W1 = (const float*)d_in[1];
    const float* b1 = (const float*)d_in[2];
    const float* W2 = (const float*)d_in[3];
    const float* b2 = (const float*)d_in[4];
    float* out = (float*)d_out;

    char* ws = (char*)d_ws;
    const i64 TENB = (i64)67108864;                       // f16 full tensor bytes
    const i64 HALFB = (i64)33554432;                      // f16 half tensor bytes
    f16* Weff  = (f16*)(ws);                              // 512 KB
    float* beff = (float*)(ws + 524288);                  // 2 KB (pad to 4 KB)
    f16* W1t  = (f16*)(ws + 528384);                      // 512 KB
    f16* W2h  = (f16*)(ws + 1052672);                     // 512 KB
    float* zrs = (float*)(ws + 1576960);                  // 2 KB (pad to 4 KB)
    f16* xh     = (f16*)(ws + 1581056);                   // 67.1 MB
    f16* logits = (f16*)(ws + 1581056 + TENB);            // 67.1 MB
    f16* conv0  = (f16*)(ws + 1581056 + 2 * TENB);        // 33.6 MB (f16 half planes)
    f16* conv1  = (f16*)(ws + 1581056 + 2 * TENB + HALFB);// 33.6 MB  (~203 MB total)

    // L1: x-tcvt || W1^T-tcvt || W2-cvt || zeros || beff
    k_pre2<<<dim3(8387), dim3(256), 0, stream>>>(x, xh, W1, W1t, W2, W2h, zrs, b1, b2, beff);
    // L2: Weff = W2 @ W1 via MFMA
    k_rgemm<<<dim3(4, 4, 1), dim3(256), 0, stream>>>(W1t, W2h, zrs, Weff);
    // L3: logits = Weff @ X + beff
    k_rgemm<<<dim3(TB / 128, FB / 128, 256), dim3(256), 0, stream>>>(Weff, xh, beff, logits);
    // L4: chunk-0 fftconv -> conv0 (f16)
    k_fftconv<<<dim3(32, 64), dim3(256), 0, stream>>>(xh, logits, conv0, 0, 0);
    // L5: chunk-1 fftconv -> conv1 || transpose conv0 -> out[0:128]
    k_mid<<<dim3(6144), dim3(256), 0, stream>>>(xh, logits, conv1, conv0, out);
    // L6: transpose conv1 -> out[128:256]
    k_transpose_out<<<dim3(4, 8, 128), dim3(256), 0, stream>>>(conv1, out, 128);
}

// Round 13
// 227.481 us; speedup vs baseline: 1.2659x; 1.0780x over previous
//
#include <hip/hip_runtime.h>
#include <math.h>

#define FB 512
#define TB 256
#define PLANE (FB * TB)
typedef long long i64;
typedef _Float16 f16;
typedef _Float16 f16x8 __attribute__((ext_vector_type(8)));
typedef _Float16 f16x4 __attribute__((ext_vector_type(4)));
typedef float f32x4 __attribute__((ext_vector_type(4)));

#define MFMA16(a, b, c) __builtin_amdgcn_mfma_f32_16x16x32_f16(a, b, c, 0, 0, 0)

// ---------- generic 64x64 transpose+cvt tile: dst[c0+t][r0+f] = src[r0+f][c0+t]
__device__ __forceinline__ void tcvt_tile(const float* __restrict__ src,
                                          f16* __restrict__ dst,
                                          int sstride, int dstride,
                                          int r0, int c0, int tid,
                                          float (*ld)[65]) {
    const int lrr = tid >> 4, lc = (tid & 15) * 4;
    f32x4 v0 = *(const f32x4*)&src[(i64)(r0 + lrr + 0) * sstride + c0 + lc];
    f32x4 v1 = *(const f32x4*)&src[(i64)(r0 + lrr + 16) * sstride + c0 + lc];
    f32x4 v2 = *(const f32x4*)&src[(i64)(r0 + lrr + 32) * sstride + c0 + lc];
    f32x4 v3 = *(const f32x4*)&src[(i64)(r0 + lrr + 48) * sstride + c0 + lc];
#pragma unroll
    for (int j = 0; j < 4; ++j) {
        ld[lrr + 0][lc + j] = v0[j];
        ld[lrr + 16][lc + j] = v1[j];
        ld[lrr + 32][lc + j] = v2[j];
        ld[lrr + 48][lc + j] = v3[j];
    }
    __syncthreads();
    const int tr2 = tid >> 3, fc = (tid & 7) * 8;
#pragma unroll
    for (int pass = 0; pass < 2; ++pass) {
        const int t = tr2 + pass * 32;
        f16x8 o;
#pragma unroll
        for (int j = 0; j < 8; ++j) o[j] = (f16)ld[fc + j][t];
        *(f16x8*)&dst[(i64)(c0 + t) * dstride + r0 + fc] = o;
    }
}

// ================= prologue: x-tcvt || W1^T-tcvt || W2 cvt || zeros || beff ===
// beff branch is wave-parallel coalesced matvec (r12: the old 2-block scalar
// version with 2KB-stride lane loads ran as a ~40us serial TAIL after the
// 8192 transpose blocks drained — dispatch dur = max over branches).
__global__ __launch_bounds__(256) void k_pre2(const float* __restrict__ X,
                                              f16* __restrict__ O,
                                              const float* __restrict__ W1,
                                              f16* __restrict__ W1t,
                                              const float* __restrict__ W2,
                                              f16* __restrict__ W2h,
                                              float* __restrict__ zrs,
                                              const float* __restrict__ b1,
                                              const float* __restrict__ b2,
                                              float* __restrict__ beff) {
    __shared__ float ld[64][65];
    const int bid = blockIdx.x;
    const int tid = threadIdx.x;
    if (bid < 8192) {
        const int p = bid >> 5;
        const int f0 = ((bid >> 2) & 7) * 64, t0 = (bid & 3) * 64;
        tcvt_tile(X + (i64)p * PLANE, O + (i64)p * PLANE, TB, FB, f0, t0, tid, ld);
    } else if (bid < 8256) {
        const int w = bid - 8192;
        tcvt_tile(W1, W1t, FB, FB, (w >> 3) * 64, (w & 7) * 64, tid, ld);
    } else if (bid < 8384) {
        const i64 idx = ((i64)(bid - 8256) * 256 + tid) * 8;
        const float4 a = *(const float4*)&W2[idx];
        const float4 b = *(const float4*)&W2[idx + 4];
        f16x8 o;
        o[0] = (f16)a.x; o[1] = (f16)a.y; o[2] = (f16)a.z; o[3] = (f16)a.w;
        o[4] = (f16)b.x; o[5] = (f16)b.y; o[6] = (f16)b.z; o[7] = (f16)b.w;
        *(f16x8*)&W2h[idx] = o;
    } else if (bid == 8384) {
        zrs[tid] = 0.f;
        zrs[tid + 256] = 0.f;
    } else {
        // beff[m] = dot(W2[m,:], b1) + b2[m]; one m per wave, coalesced.
        const int m = (bid - 8385) * 4 + (tid >> 6);
        const int lane = tid & 63;
        const float* w2r = W2 + (i64)m * FB + lane * 8;
        const f32x4 a0 = *(const f32x4*)(w2r);
        const f32x4 a1 = *(const f32x4*)(w2r + 4);
        const f32x4 c0 = *(const f32x4*)(b1 + lane * 8);
        const f32x4 c1 = *(const f32x4*)(b1 + lane * 8 + 4);
        float acc = 0.f;
#pragma unroll
        for (int j = 0; j < 4; ++j) acc = fmaf(a0[j], c0[j], acc);
#pragma unroll
        for (int j = 0; j < 4; ++j) acc = fmaf(a1[j], c1[j], acc);
#pragma unroll
        for (int o = 32; o > 0; o >>= 1) acc += __shfl_xor(acc, o);
        if (lane == 0) beff[m] = acc + b2[m];
    }
}

// ---------- real MFMA GEMM: Out[t][m] (f16) = sum_k A[m][k]*In[t][k] + bias[m]
// Also used for Weff = W2@W1: A=W1t, In=W2h, bias=0 -> Out[m][kk]=Weff.
__global__ __launch_bounds__(256, 2) void k_rgemm(const f16* __restrict__ A,
                                                  const f16* __restrict__ In,
                                                  const float* __restrict__ bias,
                                                  f16* __restrict__ Out) {
    __shared__ f16 Asx[128][40], Bsx[128][40];
    const int slab = blockIdx.z;
    const f16* Bsrc = In + (i64)slab * PLANE;
    f16* Odst = Out + (i64)slab * PLANE;
    const int t0 = blockIdx.x * 128, m0 = blockIdx.y * 128;
    const int tid = threadIdx.x;
    const int wave = tid >> 6, lane = tid & 63;
    const int wm = wave >> 1, wn = wave & 1;
    const int lr = lane & 15, lg = lane >> 4;
    const int srow = tid >> 2, sgrp = (tid & 3) * 8;

    f32x4 acc[4][4] = {};
    f16x8 nA[2], nB[2];
#pragma unroll
    for (int i = 0; i < 2; ++i) {
        const int row = i * 64 + srow;
        nA[i] = *(const f16x8*)(A + (i64)(m0 + row) * FB + sgrp);
        nB[i] = *(const f16x8*)(Bsrc + (i64)(t0 + row) * FB + sgrp);
    }
#pragma unroll
    for (int i = 0; i < 2; ++i) {
        const int row = i * 64 + srow;
        *(f16x8*)&Asx[row][sgrp] = nA[i];
        *(f16x8*)&Bsx[row][sgrp] = nB[i];
    }
    __syncthreads();

#pragma unroll 1
    for (int kt = 0; kt < 16; ++kt) {
        if (kt < 15) {
            const int k0 = (kt + 1) * 32;
#pragma unroll
            for (int i = 0; i < 2; ++i) {
                const int row = i * 64 + srow;
                nA[i] = *(const f16x8*)(A + (i64)(m0 + row) * FB + k0 + sgrp);
                nB[i] = *(const f16x8*)(Bsrc + (i64)(t0 + row) * FB + k0 + sgrp);
            }
        }
        f16x8 aA[4], bB[4];
#pragma unroll
        for (int mf = 0; mf < 4; ++mf)
            aA[mf] = *(const f16x8*)&Asx[wm * 64 + mf * 16 + lr][lg * 8];
#pragma unroll
        for (int nf = 0; nf < 4; ++nf)
            bB[nf] = *(const f16x8*)&Bsx[wn * 64 + nf * 16 + lr][lg * 8];
#pragma unroll
        for (int nf = 0; nf < 4; ++nf)
#pragma unroll
            for (int mf = 0; mf < 4; ++mf)
                acc[mf][nf] = MFMA16(aA[mf], bB[nf], acc[mf][nf]);
        __syncthreads();
        if (kt < 15) {
#pragma unroll
            for (int i = 0; i < 2; ++i) {
                const int row = i * 64 + srow;
                *(f16x8*)&Asx[row][sgrp] = nA[i];
                *(f16x8*)&Bsx[row][sgrp] = nB[i];
            }
        }
        __syncthreads();
    }

#pragma unroll
    for (int mf = 0; mf < 4; ++mf) {
        const int m = m0 + wm * 64 + mf * 16 + lg * 4;
        const float4 bv = *(const float4*)&bias[m];
        const float bb[4] = {bv.x, bv.y, bv.z, bv.w};
#pragma unroll
        for (int nf = 0; nf < 4; ++nf) {
            const int t = t0 + wn * 64 + nf * 16 + lr;
            f16x4 o;
#pragma unroll
            for (int r = 0; r < 4; ++r) o[r] = (f16)(acc[mf][nf][r] + bb[r]);
            *(f16x4*)&Odst[(i64)t * FB + m] = o;
        }
    }
}

// ================= fused softmax + conjFFT/mul/FFT, radix-8 three-step =======
// FFT arrangement: z[p] at (lane=p%64, reg=p/64). Global I/O contiguous
// (16B/lane); LDS marshal pre/post, conflict-free (r8-r9). Conv out = f16.

#define TWO_PI_OVER_512 0.012271846303085129f
#define TWO_PI_OVER_64 0.0981747704246810387f
#define R2C 0.70710678118654752f

template <int SGN>
__device__ __forceinline__ void fft8(float xr[8], float xi[8]) {
    const float sg = (float)SGN;   // W8 = e^{SGN*i*2pi/8}
    float t0r = xr[0] + xr[4], t0i = xi[0] + xi[4];
    float u0r = xr[0] - xr[4], u0i = xi[0] - xi[4];
    float t1r = xr[1] + xr[5], t1i = xi[1] + xi[5];
    float d1r = xr[1] - xr[5], d1i = xi[1] - xi[5];
    float u1r = R2C * (d1r - sg * d1i), u1i = R2C * (sg * d1r + d1i);
    float t2r = xr[2] + xr[6], t2i = xi[2] + xi[6];
    float d2r = xr[2] - xr[6], d2i = xi[2] - xi[6];
    float u2r = -sg * d2i, u2i = sg * d2r;
    float t3r = xr[3] + xr[7], t3i = xi[3] + xi[7];
    float d3r = xr[3] - xr[7], d3i = xi[3] - xi[7];
    float u3r = -R2C * (d3r + sg * d3i), u3i = R2C * (sg * d3r - d3i);
    float p0r = t0r + t2r, p0i = t0i + t2i, q0r = t0r - t2r, q0i = t0i - t2i;
    float p1r = t1r + t3r, p1i = t1i + t3i;
    float q1r = -sg * (t1i - t3i), q1i = sg * (t1r - t3r);
    float p2r = u0r + u2r, p2i = u0i + u2i, q2r = u0r - u2r, q2i = u0i - u2i;
    float p3r = u1r + u3r, p3i = u1i + u3i;
    float q3r = -sg * (u1i - u3i), q3i = sg * (u1r - u3r);
    xr[0] = p0r + p1r; xi[0] = p0i + p1i;
    xr[4] = p0r - p1r; xi[4] = p0i - p1i;
    xr[2] = q0r + q1r; xi[2] = q0i + q1i;
    xr[6] = q0r - q1r; xi[6] = q0i - q1i;
    xr[1] = p2r + p3r; xi[1] = p2i + p3i;
    xr[5] = p2r - p3r; xi[5] = p2i - p3i;
    xr[3] = q2r + q3r; xi[3] = q2i + q3i;
    xr[7] = q2r - q3r; xi[7] = q2i - q3i;
}

template <int SGN>
__device__ __forceinline__ void fft512x2(float ar[8], float ai[8],
                                         float br[8], float bi[8], int lane,
                                         float4* __restrict__ L,
                                         const float w1c[7], const float w1s[7],
                                         const float w2c[7], const float w2s[7]) {
    const float sg = (float)SGN;
    fft8<SGN>(ar, ai);
    fft8<SGN>(br, bi);
#pragma unroll
    for (int m = 1; m < 8; ++m) {
        const float wc = w1c[m - 1], ws = sg * w1s[m - 1];
        float tr = ar[m], ti = ai[m];
        ar[m] = tr * wc - ti * ws; ai[m] = tr * ws + ti * wc;
        tr = br[m]; ti = bi[m];
        br[m] = tr * wc - ti * ws; bi[m] = tr * ws + ti * wc;
    }
    // transpose 1: linear write lane*9+m ; permuted read (a8+8b8)*9+m8
#pragma unroll
    for (int m = 0; m < 8; ++m)
        L[lane * 9 + m] = make_float4(ar[m], ai[m], br[m], bi[m]);
    {
        const int a8 = lane & 7, m8 = lane >> 3;
#pragma unroll
        for (int b8 = 0; b8 < 8; ++b8) {
            const float4 v = L[(a8 + 8 * b8) * 9 + m8];
            ar[b8] = v.x; ai[b8] = v.y; br[b8] = v.z; bi[b8] = v.w;
        }
    }
    fft8<SGN>(ar, ai);
    fft8<SGN>(br, bi);
#pragma unroll
    for (int n = 1; n < 8; ++n) {
        const float wc = w2c[n - 1], ws = sg * w2s[n - 1];
        float tr = ar[n], ti = ai[n];
        ar[n] = tr * wc - ti * ws; ai[n] = tr * ws + ti * wc;
        tr = br[n]; ti = bi[n];
        br[n] = tr * wc - ti * ws; bi[n] = tr * ws + ti * wc;
    }
    // transpose 2: scatter write (m+8n)*9+a ; linear read lane*9+j
    {
        const int a2 = lane & 7, m2 = lane >> 3;
#pragma unroll
        for (int n = 0; n < 8; ++n)
            L[(m2 + 8 * n) * 9 + a2] = make_float4(ar[n], ai[n], br[n], bi[n]);
    }
#pragma unroll
    for (int j = 0; j < 8; ++j) {
        const float4 v = L[lane * 9 + j];
        ar[j] = v.x; ai[j] = v.y; br[j] = v.z; bi[j] = v.w;
    }
    fft8<SGN>(ar, ai);
    fft8<SGN>(br, bi);
}

__device__ __forceinline__ float wave_max(float v) {
#pragma unroll
    for (int m = 1; m <= 32; m <<= 1) v = fmaxf(v, __shfl_xor(v, m));
    return v;
}
__device__ __forceinline__ float wave_sum(float v) {
#pragma unroll
    for (int m = 1; m <= 32; m <<= 1) v += __shfl_xor(v, m);
    return v;
}

__device__ __forceinline__ void softmax8(float w[8]) {
    float mx = w[0];
#pragma unroll
    for (int j = 1; j < 8; ++j) mx = fmaxf(mx, w[j]);
    mx = wave_max(mx);
    float sm = 0.f;
#pragma unroll
    for (int j = 0; j < 8; ++j) { w[j] = __expf(w[j] - mx); sm += w[j]; }
    sm = wave_sum(sm);
    const float inv = 1.0f / sm;
#pragma unroll
    for (int j = 0; j < 8; ++j) w[j] *= inv;
}

__device__ __forceinline__ void load_marshal(const f16* __restrict__ Hre,
                                             const f16* __restrict__ Him,
                                             const f16* __restrict__ Wre,
                                             const f16* __restrict__ Wim,
                                             i64 rowbase, int lane,
                                             float4* __restrict__ L,
                                             float hr[8], float hi2[8],
                                             float wr[8], float wi[8]) {
    const f16x8 vhr = *(const f16x8*)(Hre + rowbase + 8 * lane);
    const f16x8 vhi = *(const f16x8*)(Him + rowbase + 8 * lane);
    const f16x8 vwr = *(const f16x8*)(Wre + rowbase + 8 * lane);
    const f16x8 vwi = *(const f16x8*)(Wim + rowbase + 8 * lane);
#pragma unroll
    for (int j = 0; j < 8; ++j)
        L[lane * 9 + j] = make_float4((float)vhr[j], (float)vhi[j],
                                      (float)vwr[j], (float)vwi[j]);
    const int c = lane >> 3, q = lane & 7;
#pragma unroll
    for (int v = 0; v < 8; ++v) {
        const float4 f4 = L[(8 * v + c) * 9 + q];
        hr[v] = f4.x; hi2[v] = f4.y; wr[v] = f4.z; wi[v] = f4.w;
    }
}

__device__ __forceinline__ void fftconv_block(const f16* __restrict__ xh,
                                              const f16* __restrict__ logits,
                                              f16* __restrict__ conv,
                                              int tblk, int cs, int chunkoff,
                                              int wave, int lane, float4* L) {
    const int b = cs >> 4, d = cs & 15;
    const int pre = b * 32 + d;
    const int pim = pre + 16;

    float w1c[7], w1s[7], w2c[7], w2s[7];
    {
        float s1, c1;
        __sincosf((float)lane * TWO_PI_OVER_512, &s1, &c1);
        w1c[0] = c1; w1s[0] = s1;
#pragma unroll
        for (int m = 1; m < 7; ++m) {
            const float pc = w1c[m - 1], ps = w1s[m - 1];
            w1c[m] = pc * c1 - ps * s1;
            w1s[m] = pc * s1 + ps * c1;
        }
        float s2, c2;
        __sincosf((float)(lane & 7) * TWO_PI_OVER_64, &s2, &c2);
        w2c[0] = c2; w2s[0] = s2;
#pragma unroll
        for (int n = 1; n < 7; ++n) {
            const float pc = w2c[n - 1], ps = w2s[n - 1];
            w2c[n] = pc * c2 - ps * s2;
            w2s[n] = pc * s2 + ps * c2;
        }
    }

    const f16* Hre = xh + (i64)pre * PLANE;
    const f16* Him = xh + (i64)pim * PLANE;
    const f16* Wre = logits + (i64)pre * PLANE;
    const f16* Wim = logits + (i64)pim * PLANE;
    f16* Cre = conv + (i64)(pre - chunkoff) * PLANE;
    f16* Cim = conv + (i64)(pim - chunkoff) * PLANE;

    const int t1a = tblk * 8 + wave * 2;

    float p0r[8], p0i[8], p1r[8], p1i[8];
    {
        float hr[8], hi2[8], wr[8], wi[8];
        load_marshal(Hre, Him, Wre, Wim, (i64)t1a * FB, lane, L, hr, hi2, wr, wi);
        softmax8(wr);
        softmax8(wi);
        fft512x2<1>(hr, hi2, wr, wi, lane, L, w1c, w1s, w2c, w2s);
#pragma unroll
        for (int j = 0; j < 8; ++j) {
            p0r[j] = (hr[j] * wr[j] - hi2[j] * wi[j]) * (1.0f / 512.0f);
            p0i[j] = (hr[j] * wi[j] + hi2[j] * wr[j]) * (1.0f / 512.0f);
        }
    }
    {
        float hr[8], hi2[8], wr[8], wi[8];
        load_marshal(Hre, Him, Wre, Wim, (i64)(t1a + 1) * FB, lane, L, hr, hi2, wr, wi);
        softmax8(wr);
        softmax8(wi);
        fft512x2<1>(hr, hi2, wr, wi, lane, L, w1c, w1s, w2c, w2s);
#pragma unroll
        for (int j = 0; j < 8; ++j) {
            p1r[j] = (hr[j] * wr[j] - hi2[j] * wi[j]) * (1.0f / 512.0f);
            p1i[j] = (hr[j] * wi[j] + hi2[j] * wr[j]) * (1.0f / 512.0f);
        }
    }
    fft512x2<-1>(p0r, p0i, p1r, p1i, lane, L, w1c, w1s, w2c, w2s);

    // post-transpose -> contiguous f16x8 (16B/lane) stores
    {
        const int a = lane & 7, bq = lane >> 3;
#pragma unroll
        for (int s = 0; s < 8; ++s)
            L[(bq + 8 * s) * 9 + a] = make_float4(p0r[s], p0i[s], p1r[s], p1i[s]);
    }
    f16x8 o0r, o0i, o1r, o1i;
#pragma unroll
    for (int j = 0; j < 8; ++j) {
        const float4 g = L[lane * 9 + j];
        o0r[j] = (f16)g.x; o0i[j] = (f16)g.y;
        o1r[j] = (f16)g.z; o1i[j] = (f16)g.w;
    }
    *(f16x8*)(Cre + (i64)t1a * FB + 8 * lane) = o0r;
    *(f16x8*)(Cim + (i64)t1a * FB + 8 * lane) = o0i;
    *(f16x8*)(Cre + (i64)(t1a + 1) * FB + 8 * lane) = o1r;
    *(f16x8*)(Cim + (i64)(t1a + 1) * FB + 8 * lane) = o1i;
}

// transpose_out body: f16 [t][f] chunk plane p -> f32 [f][t] out plane p+pbase
__device__ __forceinline__ void transpose_block(const f16* __restrict__ C,
                                                float* __restrict__ O,
                                                int tb, int fb, int p, int pbase,
                                                int tid, float (*ld)[65]) {
    const f16* src = C + (i64)p * PLANE;
    float* dst = O + (i64)(p + pbase) * PLANE;
    const int t0 = tb * 64, f0 = fb * 64;
    const int tr = tid >> 3, fc = (tid & 7) * 8;
    f16x8 u0 = *(const f16x8*)&src[(i64)(t0 + tr) * FB + f0 + fc];
    f16x8 u1 = *(const f16x8*)&src[(i64)(t0 + tr + 32) * FB + f0 + fc];
#pragma unroll
    for (int j = 0; j < 8; ++j) {
        ld[fc + j][tr] = (float)u0[j];
        ld[fc + j][tr + 32] = (float)u1[j];
    }
    __syncthreads();
    const int fr = tid >> 4, tc = (tid & 15) * 4;
#pragma unroll
    for (int i = 0; i < 4; ++i) {
        const int f = fr + i * 16;
        float4 o;
        o.x = ld[f][tc + 0]; o.y = ld[f][tc + 1];
        o.z = ld[f][tc + 2]; o.w = ld[f][tc + 3];
        *(float4*)&dst[(i64)(f0 + f) * TB + t0 + tc] = o;
    }
}

// ---------- fftconv launcher (csbase/chunkoff parametric)
__global__ __launch_bounds__(256, 2) void k_fftconv(const f16* __restrict__ xh,
                                                    const f16* __restrict__ logits,
                                                    f16* __restrict__ conv,
                                                    int csbase, int chunkoff) {
    __shared__ float4 LDS[4][576];
    const int wave = threadIdx.x >> 6, lane = threadIdx.x & 63;
    fftconv_block(xh, logits, conv, blockIdx.x, blockIdx.y + csbase, chunkoff,
                  wave, lane, LDS[wave]);
}

// ---------- role-split mid: fftconv(pairs 64..127 -> conv1) || transpose(conv0 -> out)
__global__ __launch_bounds__(256, 2) void k_mid(const f16* __restrict__ xh,
                                                const f16* __restrict__ logits,
                                                f16* __restrict__ conv1,
                                                const f16* __restrict__ conv0,
                                                float* __restrict__ out) {
    __shared__ __align__(16) char raw[36864];
    const int bid = blockIdx.x;
    const int tid = threadIdx.x;
    if (bid < 2048) {
        const int wave = tid >> 6, lane = tid & 63;
        float4* L = (float4*)raw + wave * 576;
        fftconv_block(xh, logits, conv1, bid & 31, 64 + (bid >> 5), 128, wave, lane, L);
    } else {
        const int w = bid - 2048;
        float (*ld)[65] = (float(*)[65])raw;
        transpose_block(conv0, out, w & 3, (w >> 2) & 7, w >> 5, 0, tid, ld);
    }
}

// ---------- final transpose
__global__ __launch_bounds__(256) void k_transpose_out(const f16* __restrict__ C,
                                                       float* __restrict__ O,
                                                       int pbase) {
    __shared__ float ld[64][65];
    transpose_block(C, O, blockIdx.x, blockIdx.y, blockIdx.z, pbase, threadIdx.x, ld);
}

extern "C" void kernel_launch(void* const* d_in, const int* in_sizes, int n_in,
                              void* d_out, int out_size, void* d_ws, size_t ws_size,
                              hipStream_t stream) {
    (void)in_sizes; (void)n_in; (void)out_size; (void)ws_size;
    const float* x = (const float*)d_in[0];
    const float* W1 = (const float*)d_in[1];
    const float* b1 = (const float*)d_in[2];
    const float* W2 = (const float*)d_in[3];
    const float* b2 = (const float*)d_in[4];
    float* out = (float*)d_out;

    char* ws = (char*)d_ws;
    const i64 TENB = (i64)67108864;                       // f16 full tensor bytes
    const i64 HALFB = (i64)33554432;                      // f16 half tensor bytes
    f16* Weff  = (f16*)(ws);                              // 512 KB
    float* beff = (float*)(ws + 524288);                  // 2 KB (pad to 4 KB)
    f16* W1t  = (f16*)(ws + 528384);                      // 512 KB
    f16* W2h  = (f16*)(ws + 1052672);                     // 512 KB
    float* zrs = (float*)(ws + 1576960);                  // 2 KB (pad to 4 KB)
    f16* xh     = (f16*)(ws + 1581056);                   // 67.1 MB
    f16* logits = (f16*)(ws + 1581056 + TENB);            // 67.1 MB
    f16* conv0  = (f16*)(ws + 1581056 + 2 * TENB);        // 33.6 MB (f16 half planes)
    f16* conv1  = (f16*)(ws + 1581056 + 2 * TENB + HALFB);// 33.6 MB  (~203 MB total)

    // L1: x-tcvt || W1^T-tcvt || W2-cvt || zeros || beff (wave-parallel)
    k_pre2<<<dim3(8513), dim3(256), 0, stream>>>(x, xh, W1, W1t, W2, W2h, zrs, b1, b2, beff);
    // L2: Weff = W2 @ W1 via MFMA
    k_rgemm<<<dim3(4, 4, 1), dim3(256), 0, stream>>>(W1t, W2h, zrs, Weff);
    // L3: logits = Weff @ X + beff
    k_rgemm<<<dim3(TB / 128, FB / 128, 256), dim3(256), 0, stream>>>(Weff, xh, beff, logits);
    // L4: chunk-0 fftconv -> conv0 (f16)
    k_fftconv<<<dim3(32, 64), dim3(256), 0, stream>>>(xh, logits, conv0, 0, 0);
    // L5: chunk-1 fftconv -> conv1 || transpose conv0 -> out[0:128]
    k_mid<<<dim3(6144), dim3(256), 0, stream>>>(xh, logits, conv1, conv0, out);
    // L6: transpose conv1 -> out[128:256]
    k_transpose_out<<<dim3(4, 8, 128), dim3(256), 0, stream>>>(conv1, out, 128);
}

// Round 14
// 220.896 us; speedup vs baseline: 1.3036x; 1.0298x over previous
//
#include <hip/hip_runtime.h>
#include <math.h>

#define FB 512
#define TB 256
#define PLANE (FB * TB)
typedef long long i64;
typedef _Float16 f16;
typedef _Float16 f16x8 __attribute__((ext_vector_type(8)));
typedef _Float16 f16x4 __attribute__((ext_vector_type(4)));
typedef float f32x4 __attribute__((ext_vector_type(4)));

#define MFMA16(a, b, c) __builtin_amdgcn_mfma_f32_16x16x32_f16(a, b, c, 0, 0, 0)

// ---------- generic 64x64 transpose+cvt tile: dst[c0+t][r0+f] = src[r0+f][c0+t]
__device__ __forceinline__ void tcvt_tile(const float* __restrict__ src,
                                          f16* __restrict__ dst,
                                          int sstride, int dstride,
                                          int r0, int c0, int tid,
                                          float (*ld)[65]) {
    const int lrr = tid >> 4, lc = (tid & 15) * 4;
    f32x4 v0 = *(const f32x4*)&src[(i64)(r0 + lrr + 0) * sstride + c0 + lc];
    f32x4 v1 = *(const f32x4*)&src[(i64)(r0 + lrr + 16) * sstride + c0 + lc];
    f32x4 v2 = *(const f32x4*)&src[(i64)(r0 + lrr + 32) * sstride + c0 + lc];
    f32x4 v3 = *(const f32x4*)&src[(i64)(r0 + lrr + 48) * sstride + c0 + lc];
#pragma unroll
    for (int j = 0; j < 4; ++j) {
        ld[lrr + 0][lc + j] = v0[j];
        ld[lrr + 16][lc + j] = v1[j];
        ld[lrr + 32][lc + j] = v2[j];
        ld[lrr + 48][lc + j] = v3[j];
    }
    __syncthreads();
    const int tr2 = tid >> 3, fc = (tid & 7) * 8;
#pragma unroll
    for (int pass = 0; pass < 2; ++pass) {
        const int t = tr2 + pass * 32;
        f16x8 o;
#pragma unroll
        for (int j = 0; j < 8; ++j) o[j] = (f16)ld[fc + j][t];
        *(f16x8*)&dst[(i64)(c0 + t) * dstride + r0 + fc] = o;
    }
}

// ================= prologue: x-tcvt || W1^T-tcvt || W2 cvt || zeros || beff ===
__global__ __launch_bounds__(256) void k_pre2(const float* __restrict__ X,
                                              f16* __restrict__ O,
                                              const float* __restrict__ W1,
                                              f16* __restrict__ W1t,
                                              const float* __restrict__ W2,
                                              f16* __restrict__ W2h,
                                              float* __restrict__ zrs,
                                              const float* __restrict__ b1,
                                              const float* __restrict__ b2,
                                              float* __restrict__ beff) {
    __shared__ float ld[64][65];
    const int bid = blockIdx.x;
    const int tid = threadIdx.x;
    if (bid < 8192) {
        const int p = bid >> 5;
        const int f0 = ((bid >> 2) & 7) * 64, t0 = (bid & 3) * 64;
        tcvt_tile(X + (i64)p * PLANE, O + (i64)p * PLANE, TB, FB, f0, t0, tid, ld);
    } else if (bid < 8256) {
        const int w = bid - 8192;
        tcvt_tile(W1, W1t, FB, FB, (w >> 3) * 64, (w & 7) * 64, tid, ld);
    } else if (bid < 8384) {
        const i64 idx = ((i64)(bid - 8256) * 256 + tid) * 8;
        const float4 a = *(const float4*)&W2[idx];
        const float4 b = *(const float4*)&W2[idx + 4];
        f16x8 o;
        o[0] = (f16)a.x; o[1] = (f16)a.y; o[2] = (f16)a.z; o[3] = (f16)a.w;
        o[4] = (f16)b.x; o[5] = (f16)b.y; o[6] = (f16)b.z; o[7] = (f16)b.w;
        *(f16x8*)&W2h[idx] = o;
    } else if (bid == 8384) {
        zrs[tid] = 0.f;
        zrs[tid + 256] = 0.f;
    } else {
        // beff[m] = dot(W2[m,:], b1) + b2[m]; one m per wave, coalesced.
        const int m = (bid - 8385) * 4 + (tid >> 6);
        const int lane = tid & 63;
        const float* w2r = W2 + (i64)m * FB + lane * 8;
        const f32x4 a0 = *(const f32x4*)(w2r);
        const f32x4 a1 = *(const f32x4*)(w2r + 4);
        const f32x4 c0 = *(const f32x4*)(b1 + lane * 8);
        const f32x4 c1 = *(const f32x4*)(b1 + lane * 8 + 4);
        float acc = 0.f;
#pragma unroll
        for (int j = 0; j < 4; ++j) acc = fmaf(a0[j], c0[j], acc);
#pragma unroll
        for (int j = 0; j < 4; ++j) acc = fmaf(a1[j], c1[j], acc);
#pragma unroll
        for (int o = 32; o > 0; o >>= 1) acc += __shfl_xor(acc, o);
        if (lane == 0) beff[m] = acc + b2[m];
    }
}

// ---------- real MFMA GEMM body: Out[t][m] (f16) = sum_k A[m][k]*In[t][k] + bias[m]
__device__ __forceinline__ void rgemm_body(const f16* __restrict__ A,
                                           const f16* __restrict__ In,
                                           const float* __restrict__ bias,
                                           f16* __restrict__ Out,
                                           int t0, int m0, int slab,
                                           f16 (*Asx)[40], f16 (*Bsx)[40]) {
    const f16* Bsrc = In + (i64)slab * PLANE;
    f16* Odst = Out + (i64)slab * PLANE;
    const int tid = threadIdx.x;
    const int wave = tid >> 6, lane = tid & 63;
    const int wm = wave >> 1, wn = wave & 1;
    const int lr = lane & 15, lg = lane >> 4;
    const int srow = tid >> 2, sgrp = (tid & 3) * 8;

    f32x4 acc[4][4] = {};
    f16x8 nA[2], nB[2];
#pragma unroll
    for (int i = 0; i < 2; ++i) {
        const int row = i * 64 + srow;
        nA[i] = *(const f16x8*)(A + (i64)(m0 + row) * FB + sgrp);
        nB[i] = *(const f16x8*)(Bsrc + (i64)(t0 + row) * FB + sgrp);
    }
#pragma unroll
    for (int i = 0; i < 2; ++i) {
        const int row = i * 64 + srow;
        *(f16x8*)&Asx[row][sgrp] = nA[i];
        *(f16x8*)&Bsx[row][sgrp] = nB[i];
    }
    __syncthreads();

#pragma unroll 1
    for (int kt = 0; kt < 16; ++kt) {
        if (kt < 15) {
            const int k0 = (kt + 1) * 32;
#pragma unroll
            for (int i = 0; i < 2; ++i) {
                const int row = i * 64 + srow;
                nA[i] = *(const f16x8*)(A + (i64)(m0 + row) * FB + k0 + sgrp);
                nB[i] = *(const f16x8*)(Bsrc + (i64)(t0 + row) * FB + k0 + sgrp);
            }
        }
        f16x8 aA[4], bB[4];
#pragma unroll
        for (int mf = 0; mf < 4; ++mf)
            aA[mf] = *(const f16x8*)&Asx[wm * 64 + mf * 16 + lr][lg * 8];
#pragma unroll
        for (int nf = 0; nf < 4; ++nf)
            bB[nf] = *(const f16x8*)&Bsx[wn * 64 + nf * 16 + lr][lg * 8];
#pragma unroll
        for (int nf = 0; nf < 4; ++nf)
#pragma unroll
            for (int mf = 0; mf < 4; ++mf)
                acc[mf][nf] = MFMA16(aA[mf], bB[nf], acc[mf][nf]);
        __syncthreads();
        if (kt < 15) {
#pragma unroll
            for (int i = 0; i < 2; ++i) {
                const int row = i * 64 + srow;
                *(f16x8*)&Asx[row][sgrp] = nA[i];
                *(f16x8*)&Bsx[row][sgrp] = nB[i];
            }
        }
        __syncthreads();
    }

#pragma unroll
    for (int mf = 0; mf < 4; ++mf) {
        const int m = m0 + wm * 64 + mf * 16 + lg * 4;
        const float4 bv = *(const float4*)&bias[m];
        const float bb[4] = {bv.x, bv.y, bv.z, bv.w};
#pragma unroll
        for (int nf = 0; nf < 4; ++nf) {
            const int t = t0 + wn * 64 + nf * 16 + lr;
            f16x4 o;
#pragma unroll
            for (int r = 0; r < 4; ++r) o[r] = (f16)(acc[mf][nf][r] + bb[r]);
            *(f16x4*)&Odst[(i64)t * FB + m] = o;
        }
    }
}

// 3D-grid launcher (used for Weff = W2@W1: A=W1t, In=W2h, bias=0)
__global__ __launch_bounds__(256, 2) void k_rgemm(const f16* __restrict__ A,
                                                  const f16* __restrict__ In,
                                                  const float* __restrict__ bias,
                                                  f16* __restrict__ Out) {
    __shared__ f16 Asx[128][40], Bsx[128][40];
    rgemm_body(A, In, bias, Out, blockIdx.x * 128, blockIdx.y * 128, blockIdx.z,
               Asx, Bsx);
}

// XCD-grouped 1D launcher for logits GEMM: the 4 m-blocks sharing one
// In-tile (t0, slab) get the same id%8 -> same XCD L2 caches the tile once.
// id = ((G>>3)*4 + m)*8 + (G&7), G = slab*2 + t.  Bijective over 2048.
__global__ __launch_bounds__(256, 2) void k_rgemm_swz(const f16* __restrict__ A,
                                                      const f16* __restrict__ In,
                                                      const float* __restrict__ bias,
                                                      f16* __restrict__ Out) {
    __shared__ f16 Asx[128][40], Bsx[128][40];
    const int id = blockIdx.x;
    const int xcd = id & 7, q = id >> 3;
    const int m = q & 3;
    const int G = ((q >> 2) << 3) | xcd;
    rgemm_body(A, In, bias, Out, (G & 1) * 128, m * 128, G >> 1, Asx, Bsx);
}

// ================= fused softmax + conjFFT/mul/FFT, radix-8 three-step =======
// FFT arrangement: z[p] at (lane=p%64, reg=p/64). Global I/O contiguous
// (16B/lane); LDS marshal pre/post, conflict-free (r8-r9). Conv out = f16.

#define TWO_PI_OVER_512 0.012271846303085129f
#define TWO_PI_OVER_64 0.0981747704246810387f
#define R2C 0.70710678118654752f

template <int SGN>
__device__ __forceinline__ void fft8(float xr[8], float xi[8]) {
    const float sg = (float)SGN;   // W8 = e^{SGN*i*2pi/8}
    float t0r = xr[0] + xr[4], t0i = xi[0] + xi[4];
    float u0r = xr[0] - xr[4], u0i = xi[0] - xi[4];
    float t1r = xr[1] + xr[5], t1i = xi[1] + xi[5];
    float d1r = xr[1] - xr[5], d1i = xi[1] - xi[5];
    float u1r = R2C * (d1r - sg * d1i), u1i = R2C * (sg * d1r + d1i);
    float t2r = xr[2] + xr[6], t2i = xi[2] + xi[6];
    float d2r = xr[2] - xr[6], d2i = xi[2] - xi[6];
    float u2r = -sg * d2i, u2i = sg * d2r;
    float t3r = xr[3] + xr[7], t3i = xi[3] + xi[7];
    float d3r = xr[3] - xr[7], d3i = xi[3] - xi[7];
    float u3r = -R2C * (d3r + sg * d3i), u3i = R2C * (sg * d3r - d3i);
    float p0r = t0r + t2r, p0i = t0i + t2i, q0r = t0r - t2r, q0i = t0i - t2i;
    float p1r = t1r + t3r, p1i = t1i + t3i;
    float q1r = -sg * (t1i - t3i), q1i = sg * (t1r - t3r);
    float p2r = u0r + u2r, p2i = u0i + u2i, q2r = u0r - u2r, q2i = u0i - u2i;
    float p3r = u1r + u3r, p3i = u1i + u3i;
    float q3r = -sg * (u1i - u3i), q3i = sg * (u1r - u3r);
    xr[0] = p0r + p1r; xi[0] = p0i + p1i;
    xr[4] = p0r - p1r; xi[4] = p0i - p1i;
    xr[2] = q0r + q1r; xi[2] = q0i + q1i;
    xr[6] = q0r - q1r; xi[6] = q0i - q1i;
    xr[1] = p2r + p3r; xi[1] = p2i + p3i;
    xr[5] = p2r - p3r; xi[5] = p2i - p3i;
    xr[3] = q2r + q3r; xi[3] = q2i + q3i;
    xr[7] = q2r - q3r; xi[7] = q2i - q3i;
}

template <int SGN>
__device__ __forceinline__ void fft512x2(float ar[8], float ai[8],
                                         float br[8], float bi[8], int lane,
                                         float4* __restrict__ L,
                                         const float w1c[7], const float w1s[7],
                                         const float w2c[7], const float w2s[7]) {
    const float sg = (float)SGN;
    fft8<SGN>(ar, ai);
    fft8<SGN>(br, bi);
#pragma unroll
    for (int m = 1; m < 8; ++m) {
        const float wc = w1c[m - 1], ws = sg * w1s[m - 1];
        float tr = ar[m], ti = ai[m];
        ar[m] = tr * wc - ti * ws; ai[m] = tr * ws + ti * wc;
        tr = br[m]; ti = bi[m];
        br[m] = tr * wc - ti * ws; bi[m] = tr * ws + ti * wc;
    }
    // transpose 1: linear write lane*9+m ; permuted read (a8+8b8)*9+m8
#pragma unroll
    for (int m = 0; m < 8; ++m)
        L[lane * 9 + m] = make_float4(ar[m], ai[m], br[m], bi[m]);
    {
        const int a8 = lane & 7, m8 = lane >> 3;
#pragma unroll
        for (int b8 = 0; b8 < 8; ++b8) {
            const float4 v = L[(a8 + 8 * b8) * 9 + m8];
            ar[b8] = v.x; ai[b8] = v.y; br[b8] = v.z; bi[b8] = v.w;
        }
    }
    fft8<SGN>(ar, ai);
    fft8<SGN>(br, bi);
#pragma unroll
    for (int n = 1; n < 8; ++n) {
        const float wc = w2c[n - 1], ws = sg * w2s[n - 1];
        float tr = ar[n], ti = ai[n];
        ar[n] = tr * wc - ti * ws; ai[n] = tr * ws + ti * wc;
        tr = br[n]; ti = bi[n];
        br[n] = tr * wc - ti * ws; bi[n] = tr * ws + ti * wc;
    }
    // transpose 2: scatter write (m+8n)*9+a ; linear read lane*9+j
    {
        const int a2 = lane & 7, m2 = lane >> 3;
#pragma unroll
        for (int n = 0; n < 8; ++n)
            L[(m2 + 8 * n) * 9 + a2] = make_float4(ar[n], ai[n], br[n], bi[n]);
    }
#pragma unroll
    for (int j = 0; j < 8; ++j) {
        const float4 v = L[lane * 9 + j];
        ar[j] = v.x; ai[j] = v.y; br[j] = v.z; bi[j] = v.w;
    }
    fft8<SGN>(ar, ai);
    fft8<SGN>(br, bi);
}

__device__ __forceinline__ float wave_max(float v) {
#pragma unroll
    for (int m = 1; m <= 32; m <<= 1) v = fmaxf(v, __shfl_xor(v, m));
    return v;
}
__device__ __forceinline__ float wave_sum(float v) {
#pragma unroll
    for (int m = 1; m <= 32; m <<= 1) v += __shfl_xor(v, m);
    return v;
}

__device__ __forceinline__ void softmax8(float w[8]) {
    float mx = w[0];
#pragma unroll
    for (int j = 1; j < 8; ++j) mx = fmaxf(mx, w[j]);
    mx = wave_max(mx);
    float sm = 0.f;
#pragma unroll
    for (int j = 0; j < 8; ++j) { w[j] = __expf(w[j] - mx); sm += w[j]; }
    sm = wave_sum(sm);
    const float inv = 1.0f / sm;
#pragma unroll
    for (int j = 0; j < 8; ++j) w[j] *= inv;
}

__device__ __forceinline__ void load_marshal(const f16* __restrict__ Hre,
                                             const f16* __restrict__ Him,
                                             const f16* __restrict__ Wre,
                                             const f16* __restrict__ Wim,
                                             i64 rowbase, int lane,
                                             float4* __restrict__ L,
                                             float hr[8], float hi2[8],
                                             float wr[8], float wi[8]) {
    const f16x8 vhr = *(const f16x8*)(Hre + rowbase + 8 * lane);
    const f16x8 vhi = *(const f16x8*)(Him + rowbase + 8 * lane);
    const f16x8 vwr = *(const f16x8*)(Wre + rowbase + 8 * lane);
    const f16x8 vwi = *(const f16x8*)(Wim + rowbase + 8 * lane);
#pragma unroll
    for (int j = 0; j < 8; ++j)
        L[lane * 9 + j] = make_float4((float)vhr[j], (float)vhi[j],
                                      (float)vwr[j], (float)vwi[j]);
    const int c = lane >> 3, q = lane & 7;
#pragma unroll
    for (int v = 0; v < 8; ++v) {
        const float4 f4 = L[(8 * v + c) * 9 + q];
        hr[v] = f4.x; hi2[v] = f4.y; wr[v] = f4.z; wi[v] = f4.w;
    }
}

__device__ __forceinline__ void fftconv_block(const f16* __restrict__ xh,
                                              const f16* __restrict__ logits,
                                              f16* __restrict__ conv,
                                              int tblk, int cs,
                                              int wave, int lane, float4* L) {
    const int b = cs >> 4, d = cs & 15;
    const int pre = b * 32 + d;
    const int pim = pre + 16;

    float w1c[7], w1s[7], w2c[7], w2s[7];
    {
        float s1, c1;
        __sincosf((float)lane * TWO_PI_OVER_512, &s1, &c1);
        w1c[0] = c1; w1s[0] = s1;
#pragma unroll
        for (int m = 1; m < 7; ++m) {
            const float pc = w1c[m - 1], ps = w1s[m - 1];
            w1c[m] = pc * c1 - ps * s1;
            w1s[m] = pc * s1 + ps * c1;
        }
        float s2, c2;
        __sincosf((float)(lane & 7) * TWO_PI_OVER_64, &s2, &c2);
        w2c[0] = c2; w2s[0] = s2;
#pragma unroll
        for (int n = 1; n < 7; ++n) {
            const float pc = w2c[n - 1], ps = w2s[n - 1];
            w2c[n] = pc * c2 - ps * s2;
            w2s[n] = pc * s2 + ps * c2;
        }
    }

    const f16* Hre = xh + (i64)pre * PLANE;
    const f16* Him = xh + (i64)pim * PLANE;
    const f16* Wre = logits + (i64)pre * PLANE;
    const f16* Wim = logits + (i64)pim * PLANE;
    f16* Cre = conv + (i64)pre * PLANE;
    f16* Cim = conv + (i64)pim * PLANE;

    const int t1a = tblk * 8 + wave * 2;

    float p0r[8], p0i[8], p1r[8], p1i[8];
    {
        float hr[8], hi2[8], wr[8], wi[8];
        load_marshal(Hre, Him, Wre, Wim, (i64)t1a * FB, lane, L, hr, hi2, wr, wi);
        softmax8(wr);
        softmax8(wi);
        fft512x2<1>(hr, hi2, wr, wi, lane, L, w1c, w1s, w2c, w2s);
#pragma unroll
        for (int j = 0; j < 8; ++j) {
            p0r[j] = (hr[j] * wr[j] - hi2[j] * wi[j]) * (1.0f / 512.0f);
            p0i[j] = (hr[j] * wi[j] + hi2[j] * wr[j]) * (1.0f / 512.0f);
        }
    }
    {
        float hr[8], hi2[8], wr[8], wi[8];
        load_marshal(Hre, Him, Wre, Wim, (i64)(t1a + 1) * FB, lane, L, hr, hi2, wr, wi);
        softmax8(wr);
        softmax8(wi);
        fft512x2<1>(hr, hi2, wr, wi, lane, L, w1c, w1s, w2c, w2s);
#pragma unroll
        for (int j = 0; j < 8; ++j) {
            p1r[j] = (hr[j] * wr[j] - hi2[j] * wi[j]) * (1.0f / 512.0f);
            p1i[j] = (hr[j] * wi[j] + hi2[j] * wr[j]) * (1.0f / 512.0f);
        }
    }
    fft512x2<-1>(p0r, p0i, p1r, p1i, lane, L, w1c, w1s, w2c, w2s);

    // post-transpose -> contiguous f16x8 (16B/lane) stores
    {
        const int a = lane & 7, bq = lane >> 3;
#pragma unroll
        for (int s = 0; s < 8; ++s)
            L[(bq + 8 * s) * 9 + a] = make_float4(p0r[s], p0i[s], p1r[s], p1i[s]);
    }
    f16x8 o0r, o0i, o1r, o1i;
#pragma unroll
    for (int j = 0; j < 8; ++j) {
        const float4 g = L[lane * 9 + j];
        o0r[j] = (f16)g.x; o0i[j] = (f16)g.y;
        o1r[j] = (f16)g.z; o1i[j] = (f16)g.w;
    }
    *(f16x8*)(Cre + (i64)t1a * FB + 8 * lane) = o0r;
    *(f16x8*)(Cim + (i64)t1a * FB + 8 * lane) = o0i;
    *(f16x8*)(Cre + (i64)(t1a + 1) * FB + 8 * lane) = o1r;
    *(f16x8*)(Cim + (i64)(t1a + 1) * FB + 8 * lane) = o1i;
}

// Single-pass fftconv over all 128 pairs, XCD-swizzled: each XCD owns 16
// consecutive cs (its 32-t-block groups stay L2-local).
// id = (((cs&15)<<5 | t) << 3) | (cs>>4).  Bijective over 4096.
__global__ __launch_bounds__(256, 2) void k_fftconv_all(const f16* __restrict__ xh,
                                                        const f16* __restrict__ logits,
                                                        f16* __restrict__ conv) {
    __shared__ float4 LDS[4][576];
    const int id = blockIdx.x;
    const int xcd = id & 7, r = id >> 3;
    const int tblk = r & 31;
    const int cs = (xcd << 4) | (r >> 5);
    const int wave = threadIdx.x >> 6, lane = threadIdx.x & 63;
    fftconv_block(xh, logits, conv, tblk, cs, wave, lane, LDS[wave]);
}

// transpose_out: f16 [t][f] conv plane p -> f32 [f][t] out plane p
__global__ __launch_bounds__(256) void k_transpose_out(const f16* __restrict__ C,
                                                       float* __restrict__ O) {
    __shared__ float ld[64][65];
    const int tid = threadIdx.x;
    const int p = blockIdx.z;
    const f16* src = C + (i64)p * PLANE;
    float* dst = O + (i64)p * PLANE;
    const int t0 = blockIdx.x * 64, f0 = blockIdx.y * 64;
    const int tr = tid >> 3, fc = (tid & 7) * 8;
    f16x8 u0 = *(const f16x8*)&src[(i64)(t0 + tr) * FB + f0 + fc];
    f16x8 u1 = *(const f16x8*)&src[(i64)(t0 + tr + 32) * FB + f0 + fc];
#pragma unroll
    for (int j = 0; j < 8; ++j) {
        ld[fc + j][tr] = (float)u0[j];
        ld[fc + j][tr + 32] = (float)u1[j];
    }
    __syncthreads();
    const int fr = tid >> 4, tc = (tid & 15) * 4;
#pragma unroll
    for (int i = 0; i < 4; ++i) {
        const int f = fr + i * 16;
        float4 o;
        o.x = ld[f][tc + 0]; o.y = ld[f][tc + 1];
        o.z = ld[f][tc + 2]; o.w = ld[f][tc + 3];
        *(float4*)&dst[(i64)(f0 + f) * TB + t0 + tc] = o;
    }
}

extern "C" void kernel_launch(void* const* d_in, const int* in_sizes, int n_in,
                              void* d_out, int out_size, void* d_ws, size_t ws_size,
                              hipStream_t stream) {
    (void)in_sizes; (void)n_in; (void)out_size; (void)ws_size;
    const float* x = (const float*)d_in[0];
    const float* W1 = (const float*)d_in[1];
    const float* b1 = (const float*)d_in[2];
    const float* W2 = (const float*)d_in[3];
    const float* b2 = (const float*)d_in[4];
    float* out = (float*)d_out;

    char* ws = (char*)d_ws;
    const i64 TENB = (i64)67108864;                       // f16 full tensor bytes
    f16* Weff  = (f16*)(ws);                              // 512 KB
    float* beff = (float*)(ws + 524288);                  // 2 KB (pad to 4 KB)
    f16* W1t  = (f16*)(ws + 528384);                      // 512 KB
    f16* W2h  = (f16*)(ws + 1052672);                     // 512 KB
    float* zrs = (float*)(ws + 1576960);                  // 2 KB (pad to 4 KB)
    f16* xh     = (f16*)(ws + 1581056);                   // 67.1 MB
    f16* logits = (f16*)(ws + 1581056 + TENB);            // 67.1 MB
    f16* conv   = (f16*)(ws + 1581056 + 2 * TENB);        // 67.1 MB (all 256 planes f16)

    // L1: x-tcvt || W1^T-tcvt || W2-cvt || zeros || beff (wave-parallel)
    k_pre2<<<dim3(8513), dim3(256), 0, stream>>>(x, xh, W1, W1t, W2, W2h, zrs, b1, b2, beff);
    // L2: Weff = W2 @ W1 via MFMA
    k_rgemm<<<dim3(4, 4, 1), dim3(256), 0, stream>>>(W1t, W2h, zrs, Weff);
    // L3: logits = Weff @ X + beff (XCD-grouped: In-tile shared via L2)
    k_rgemm_swz<<<dim3(2048), dim3(256), 0, stream>>>(Weff, xh, beff, logits);
    // L4: fftconv all 128 pairs -> conv f16 (201 MB working set, L3-fit)
    k_fftconv_all<<<dim3(4096), dim3(256), 0, stream>>>(xh, logits, conv);
    // L5: transpose conv -> out (f32 [f][t], all 256 planes)
    k_transpose_out<<<dim3(4, 8, 256), dim3(256), 0, stream>>>(conv, out);
}

// Round 15
// 218.093 us; speedup vs baseline: 1.3204x; 1.0129x over previous
//
#include <hip/hip_runtime.h>
#include <math.h>

#define FB 512
#define TB 256
#define PLANE (FB * TB)
typedef long long i64;
typedef _Float16 f16;
typedef _Float16 f16x8 __attribute__((ext_vector_type(8)));
typedef _Float16 f16x4 __attribute__((ext_vector_type(4)));
typedef float f32x4 __attribute__((ext_vector_type(4)));

#define MFMA16(a, b, c) __builtin_amdgcn_mfma_f32_16x16x32_f16(a, b, c, 0, 0, 0)

// ---------- generic 64x64 transpose+cvt tile: dst[c0+t][r0+f] = src[r0+f][c0+t]
__device__ __forceinline__ void tcvt_tile(const float* __restrict__ src,
                                          f16* __restrict__ dst,
                                          int sstride, int dstride,
                                          int r0, int c0, int tid,
                                          float (*ld)[65]) {
    const int lrr = tid >> 4, lc = (tid & 15) * 4;
    f32x4 v0 = *(const f32x4*)&src[(i64)(r0 + lrr + 0) * sstride + c0 + lc];
    f32x4 v1 = *(const f32x4*)&src[(i64)(r0 + lrr + 16) * sstride + c0 + lc];
    f32x4 v2 = *(const f32x4*)&src[(i64)(r0 + lrr + 32) * sstride + c0 + lc];
    f32x4 v3 = *(const f32x4*)&src[(i64)(r0 + lrr + 48) * sstride + c0 + lc];
#pragma unroll
    for (int j = 0; j < 4; ++j) {
        ld[lrr + 0][lc + j] = v0[j];
        ld[lrr + 16][lc + j] = v1[j];
        ld[lrr + 32][lc + j] = v2[j];
        ld[lrr + 48][lc + j] = v3[j];
    }
    __syncthreads();
    const int tr2 = tid >> 3, fc = (tid & 7) * 8;
#pragma unroll
    for (int pass = 0; pass < 2; ++pass) {
        const int t = tr2 + pass * 32;
        f16x8 o;
#pragma unroll
        for (int j = 0; j < 8; ++j) o[j] = (f16)ld[fc + j][t];
        *(f16x8*)&dst[(i64)(c0 + t) * dstride + r0 + fc] = o;
    }
}

// ================= prologue: x-tcvt || W1^T-tcvt || W2 cvt || zeros || beff ===
__global__ __launch_bounds__(256) void k_pre2(const float* __restrict__ X,
                                              f16* __restrict__ O,
                                              const float* __restrict__ W1,
                                              f16* __restrict__ W1t,
                                              const float* __restrict__ W2,
                                              f16* __restrict__ W2h,
                                              float* __restrict__ zrs,
                                              const float* __restrict__ b1,
                                              const float* __restrict__ b2,
                                              float* __restrict__ beff) {
    __shared__ float ld[64][65];
    const int bid = blockIdx.x;
    const int tid = threadIdx.x;
    if (bid < 8192) {
        const int p = bid >> 5;
        const int f0 = ((bid >> 2) & 7) * 64, t0 = (bid & 3) * 64;
        tcvt_tile(X + (i64)p * PLANE, O + (i64)p * PLANE, TB, FB, f0, t0, tid, ld);
    } else if (bid < 8256) {
        const int w = bid - 8192;
        tcvt_tile(W1, W1t, FB, FB, (w >> 3) * 64, (w & 7) * 64, tid, ld);
    } else if (bid < 8384) {
        const i64 idx = ((i64)(bid - 8256) * 256 + tid) * 8;
        const float4 a = *(const float4*)&W2[idx];
        const float4 b = *(const float4*)&W2[idx + 4];
        f16x8 o;
        o[0] = (f16)a.x; o[1] = (f16)a.y; o[2] = (f16)a.z; o[3] = (f16)a.w;
        o[4] = (f16)b.x; o[5] = (f16)b.y; o[6] = (f16)b.z; o[7] = (f16)b.w;
        *(f16x8*)&W2h[idx] = o;
    } else if (bid == 8384) {
        zrs[tid] = 0.f;
        zrs[tid + 256] = 0.f;
    } else {
        // beff[m] = dot(W2[m,:], b1) + b2[m]; one m per wave, coalesced.
        const int m = (bid - 8385) * 4 + (tid >> 6);
        const int lane = tid & 63;
        const float* w2r = W2 + (i64)m * FB + lane * 8;
        const f32x4 a0 = *(const f32x4*)(w2r);
        const f32x4 a1 = *(const f32x4*)(w2r + 4);
        const f32x4 c0 = *(const f32x4*)(b1 + lane * 8);
        const f32x4 c1 = *(const f32x4*)(b1 + lane * 8 + 4);
        float acc = 0.f;
#pragma unroll
        for (int j = 0; j < 4; ++j) acc = fmaf(a0[j], c0[j], acc);
#pragma unroll
        for (int j = 0; j < 4; ++j) acc = fmaf(a1[j], c1[j], acc);
#pragma unroll
        for (int o = 32; o > 0; o >>= 1) acc += __shfl_xor(acc, o);
        if (lane == 0) beff[m] = acc + b2[m];
    }
}

// ---------- real MFMA GEMM body: Out[t][m] (f16) = sum_k A[m][k]*In[t][k] + bias[m]
__device__ __forceinline__ void rgemm_body(const f16* __restrict__ A,
                                           const f16* __restrict__ In,
                                           const float* __restrict__ bias,
                                           f16* __restrict__ Out,
                                           int t0, int m0, int slab,
                                           f16 (*Asx)[40], f16 (*Bsx)[40]) {
    const f16* Bsrc = In + (i64)slab * PLANE;
    f16* Odst = Out + (i64)slab * PLANE;
    const int tid = threadIdx.x;
    const int wave = tid >> 6, lane = tid & 63;
    const int wm = wave >> 1, wn = wave & 1;
    const int lr = lane & 15, lg = lane >> 4;
    const int srow = tid >> 2, sgrp = (tid & 3) * 8;

    f32x4 acc[4][4] = {};
    f16x8 nA[2], nB[2];
#pragma unroll
    for (int i = 0; i < 2; ++i) {
        const int row = i * 64 + srow;
        nA[i] = *(const f16x8*)(A + (i64)(m0 + row) * FB + sgrp);
        nB[i] = *(const f16x8*)(Bsrc + (i64)(t0 + row) * FB + sgrp);
    }
#pragma unroll
    for (int i = 0; i < 2; ++i) {
        const int row = i * 64 + srow;
        *(f16x8*)&Asx[row][sgrp] = nA[i];
        *(f16x8*)&Bsx[row][sgrp] = nB[i];
    }
    __syncthreads();

#pragma unroll 1
    for (int kt = 0; kt < 16; ++kt) {
        if (kt < 15) {
            const int k0 = (kt + 1) * 32;
#pragma unroll
            for (int i = 0; i < 2; ++i) {
                const int row = i * 64 + srow;
                nA[i] = *(const f16x8*)(A + (i64)(m0 + row) * FB + k0 + sgrp);
                nB[i] = *(const f16x8*)(Bsrc + (i64)(t0 + row) * FB + k0 + sgrp);
            }
        }
        f16x8 aA[4], bB[4];
#pragma unroll
        for (int mf = 0; mf < 4; ++mf)
            aA[mf] = *(const f16x8*)&Asx[wm * 64 + mf * 16 + lr][lg * 8];
#pragma unroll
        for (int nf = 0; nf < 4; ++nf)
            bB[nf] = *(const f16x8*)&Bsx[wn * 64 + nf * 16 + lr][lg * 8];
#pragma unroll
        for (int nf = 0; nf < 4; ++nf)
#pragma unroll
            for (int mf = 0; mf < 4; ++mf)
                acc[mf][nf] = MFMA16(aA[mf], bB[nf], acc[mf][nf]);
        __syncthreads();
        if (kt < 15) {
#pragma unroll
            for (int i = 0; i < 2; ++i) {
                const int row = i * 64 + srow;
                *(f16x8*)&Asx[row][sgrp] = nA[i];
                *(f16x8*)&Bsx[row][sgrp] = nB[i];
            }
        }
        __syncthreads();
    }

#pragma unroll
    for (int mf = 0; mf < 4; ++mf) {
        const int m = m0 + wm * 64 + mf * 16 + lg * 4;
        const float4 bv = *(const float4*)&bias[m];
        const float bb[4] = {bv.x, bv.y, bv.z, bv.w};
#pragma unroll
        for (int nf = 0; nf < 4; ++nf) {
            const int t = t0 + wn * 64 + nf * 16 + lr;
            f16x4 o;
#pragma unroll
            for (int r = 0; r < 4; ++r) o[r] = (f16)(acc[mf][nf][r] + bb[r]);
            *(f16x4*)&Odst[(i64)t * FB + m] = o;
        }
    }
}

// 3D-grid launcher (used for Weff = W2@W1: A=W1t, In=W2h, bias=0)
__global__ __launch_bounds__(256, 2) void k_rgemm(const f16* __restrict__ A,
                                                  const f16* __restrict__ In,
                                                  const float* __restrict__ bias,
                                                  f16* __restrict__ Out) {
    __shared__ f16 Asx[128][40], Bsx[128][40];
    rgemm_body(A, In, bias, Out, blockIdx.x * 128, blockIdx.y * 128, blockIdx.z,
               Asx, Bsx);
}

// XCD-grouped 1D launcher for logits GEMM (r13: +L2 tile reuse)
__global__ __launch_bounds__(256, 2) void k_rgemm_swz(const f16* __restrict__ A,
                                                      const f16* __restrict__ In,
                                                      const float* __restrict__ bias,
                                                      f16* __restrict__ Out) {
    __shared__ f16 Asx[128][40], Bsx[128][40];
    const int id = blockIdx.x;
    const int xcd = id & 7, q = id >> 3;
    const int m = q & 3;
    const int G = ((q >> 2) << 3) | xcd;
    rgemm_body(A, In, bias, Out, (G & 1) * 128, m * 128, G >> 1, Asx, Bsx);
}

// ================= fused softmax + conjFFT/mul/FFT, radix-8 three-step =======
// FFT arrangement: z[p] at (lane=p%64, reg=p/64). Global I/O contiguous;
// LDS marshal pre/post. XOR-swizzled 64x8-float4 grid (no pad): idx =
// row*8 + (col ^ (row&7)) -> 8 KB/wave, 32 KB/block => 5 blocks/CU (was
// 36.9 KB / 4 blocks with pad-to-9; occupancy was the r14 limiter).
// Conflict-free: every 8-lane phase group hits distinct idx mod 8.

#define TWO_PI_OVER_512 0.012271846303085129f
#define TWO_PI_OVER_64 0.0981747704246810387f
#define R2C 0.70710678118654752f

__device__ __forceinline__ int swz(int r, int c) { return r * 8 + (c ^ (r & 7)); }

template <int SGN>
__device__ __forceinline__ void fft8(float xr[8], float xi[8]) {
    const float sg = (float)SGN;   // W8 = e^{SGN*i*2pi/8}
    float t0r = xr[0] + xr[4], t0i = xi[0] + xi[4];
    float u0r = xr[0] - xr[4], u0i = xi[0] - xi[4];
    float t1r = xr[1] + xr[5], t1i = xi[1] + xi[5];
    float d1r = xr[1] - xr[5], d1i = xi[1] - xi[5];
    float u1r = R2C * (d1r - sg * d1i), u1i = R2C * (sg * d1r + d1i);
    float t2r = xr[2] + xr[6], t2i = xi[2] + xi[6];
    float d2r = xr[2] - xr[6], d2i = xi[2] - xi[6];
    float u2r = -sg * d2i, u2i = sg * d2r;
    float t3r = xr[3] + xr[7], t3i = xi[3] + xi[7];
    float d3r = xr[3] - xr[7], d3i = xi[3] - xi[7];
    float u3r = -R2C * (d3r + sg * d3i), u3i = R2C * (sg * d3r - d3i);
    float p0r = t0r + t2r, p0i = t0i + t2i, q0r = t0r - t2r, q0i = t0i - t2i;
    float p1r = t1r + t3r, p1i = t1i + t3i;
    float q1r = -sg * (t1i - t3i), q1i = sg * (t1r - t3r);
    float p2r = u0r + u2r, p2i = u0i + u2i, q2r = u0r - u2r, q2i = u0i - u2i;
    float p3r = u1r + u3r, p3i = u1i + u3i;
    float q3r = -sg * (u1i - u3i), q3i = sg * (u1r - u3r);
    xr[0] = p0r + p1r; xi[0] = p0i + p1i;
    xr[4] = p0r - p1r; xi[4] = p0i - p1i;
    xr[2] = q0r + q1r; xi[2] = q0i + q1i;
    xr[6] = q0r - q1r; xi[6] = q0i - q1i;
    xr[1] = p2r + p3r; xi[1] = p2i + p3i;
    xr[5] = p2r - p3r; xi[5] = p2i - p3i;
    xr[3] = q2r + q3r; xi[3] = q2i + q3i;
    xr[7] = q2r - q3r; xi[7] = q2i - q3i;
}

template <int SGN>
__device__ __forceinline__ void fft512x2(float ar[8], float ai[8],
                                         float br[8], float bi[8], int lane,
                                         float4* __restrict__ L,
                                         const float w1c[7], const float w1s[7],
                                         const float w2c[7], const float w2s[7]) {
    const float sg = (float)SGN;
    fft8<SGN>(ar, ai);
    fft8<SGN>(br, bi);
#pragma unroll
    for (int m = 1; m < 8; ++m) {
        const float wc = w1c[m - 1], ws = sg * w1s[m - 1];
        float tr = ar[m], ti = ai[m];
        ar[m] = tr * wc - ti * ws; ai[m] = tr * ws + ti * wc;
        tr = br[m]; ti = bi[m];
        br[m] = tr * wc - ti * ws; bi[m] = tr * ws + ti * wc;
    }
    // transpose 1: linear write (lane, m) ; permuted read (a8+8b8, m8)
#pragma unroll
    for (int m = 0; m < 8; ++m)
        L[swz(lane, m)] = make_float4(ar[m], ai[m], br[m], bi[m]);
    {
        const int a8 = lane & 7, m8 = lane >> 3;
#pragma unroll
        for (int b8 = 0; b8 < 8; ++b8) {
            const float4 v = L[swz(a8 + 8 * b8, m8)];
            ar[b8] = v.x; ai[b8] = v.y; br[b8] = v.z; bi[b8] = v.w;
        }
    }
    fft8<SGN>(ar, ai);
    fft8<SGN>(br, bi);
#pragma unroll
    for (int n = 1; n < 8; ++n) {
        const float wc = w2c[n - 1], ws = sg * w2s[n - 1];
        float tr = ar[n], ti = ai[n];
        ar[n] = tr * wc - ti * ws; ai[n] = tr * ws + ti * wc;
        tr = br[n]; ti = bi[n];
        br[n] = tr * wc - ti * ws; bi[n] = tr * ws + ti * wc;
    }
    // transpose 2: scatter write (m2+8n, a2) ; linear read (lane, j)
    {
        const int a2 = lane & 7, m2 = lane >> 3;
#pragma unroll
        for (int n = 0; n < 8; ++n)
            L[swz(m2 + 8 * n, a2)] = make_float4(ar[n], ai[n], br[n], bi[n]);
    }
#pragma unroll
    for (int j = 0; j < 8; ++j) {
        const float4 v = L[swz(lane, j)];
        ar[j] = v.x; ai[j] = v.y; br[j] = v.z; bi[j] = v.w;
    }
    fft8<SGN>(ar, ai);
    fft8<SGN>(br, bi);
}

__device__ __forceinline__ float wave_max(float v) {
#pragma unroll
    for (int m = 1; m <= 32; m <<= 1) v = fmaxf(v, __shfl_xor(v, m));
    return v;
}
__device__ __forceinline__ float wave_sum(float v) {
#pragma unroll
    for (int m = 1; m <= 32; m <<= 1) v += __shfl_xor(v, m);
    return v;
}

__device__ __forceinline__ void softmax8(float w[8]) {
    float mx = w[0];
#pragma unroll
    for (int j = 1; j < 8; ++j) mx = fmaxf(mx, w[j]);
    mx = wave_max(mx);
    float sm = 0.f;
#pragma unroll
    for (int j = 0; j < 8; ++j) { w[j] = __expf(w[j] - mx); sm += w[j]; }
    sm = wave_sum(sm);
    const float inv = 1.0f / sm;
#pragma unroll
    for (int j = 0; j < 8; ++j) w[j] *= inv;
}

__device__ __forceinline__ void load_marshal(const f16* __restrict__ Hre,
                                             const f16* __restrict__ Him,
                                             const f16* __restrict__ Wre,
                                             const f16* __restrict__ Wim,
                                             i64 rowbase, int lane,
                                             float4* __restrict__ L,
                                             float hr[8], float hi2[8],
                                             float wr[8], float wi[8]) {
    const f16x8 vhr = *(const f16x8*)(Hre + rowbase + 8 * lane);
    const f16x8 vhi = *(const f16x8*)(Him + rowbase + 8 * lane);
    const f16x8 vwr = *(const f16x8*)(Wre + rowbase + 8 * lane);
    const f16x8 vwi = *(const f16x8*)(Wim + rowbase + 8 * lane);
#pragma unroll
    for (int j = 0; j < 8; ++j)
        L[swz(lane, j)] = make_float4((float)vhr[j], (float)vhi[j],
                                      (float)vwr[j], (float)vwi[j]);
    const int c = lane >> 3, q = lane & 7;
#pragma unroll
    for (int v = 0; v < 8; ++v) {
        const float4 f4 = L[swz(8 * v + c, q)];
        hr[v] = f4.x; hi2[v] = f4.y; wr[v] = f4.z; wi[v] = f4.w;
    }
}

__device__ __forceinline__ void fftconv_block(const f16* __restrict__ xh,
                                              const f16* __restrict__ logits,
                                              f16* __restrict__ conv,
                                              int tblk, int cs,
                                              int wave, int lane, float4* L) {
    const int b = cs >> 4, d = cs & 15;
    const int pre = b * 32 + d;
    const int pim = pre + 16;

    float w1c[7], w1s[7], w2c[7], w2s[7];
    {
        float s1, c1;
        __sincosf((float)lane * TWO_PI_OVER_512, &s1, &c1);
        w1c[0] = c1; w1s[0] = s1;
#pragma unroll
        for (int m = 1; m < 7; ++m) {
            const float pc = w1c[m - 1], ps = w1s[m - 1];
            w1c[m] = pc * c1 - ps * s1;
            w1s[m] = pc * s1 + ps * c1;
        }
        float s2, c2;
        __sincosf((float)(lane & 7) * TWO_PI_OVER_64, &s2, &c2);
        w2c[0] = c2; w2s[0] = s2;
#pragma unroll
        for (int n = 1; n < 7; ++n) {
            const float pc = w2c[n - 1], ps = w2s[n - 1];
            w2c[n] = pc * c2 - ps * s2;
            w2s[n] = pc * s2 + ps * c2;
        }
    }

    const f16* Hre = xh + (i64)pre * PLANE;
    const f16* Him = xh + (i64)pim * PLANE;
    const f16* Wre = logits + (i64)pre * PLANE;
    const f16* Wim = logits + (i64)pim * PLANE;
    f16* Cre = conv + (i64)pre * PLANE;
    f16* Cim = conv + (i64)pim * PLANE;

    const int t1a = tblk * 8 + wave * 2;

    float p0r[8], p0i[8], p1r[8], p1i[8];
    {
        float hr[8], hi2[8], wr[8], wi[8];
        load_marshal(Hre, Him, Wre, Wim, (i64)t1a * FB, lane, L, hr, hi2, wr, wi);
        softmax8(wr);
        softmax8(wi);
        fft512x2<1>(hr, hi2, wr, wi, lane, L, w1c, w1s, w2c, w2s);
#pragma unroll
        for (int j = 0; j < 8; ++j) {
            p0r[j] = (hr[j] * wr[j] - hi2[j] * wi[j]) * (1.0f / 512.0f);
            p0i[j] = (hr[j] * wi[j] + hi2[j] * wr[j]) * (1.0f / 512.0f);
        }
    }
    {
        float hr[8], hi2[8], wr[8], wi[8];
        load_marshal(Hre, Him, Wre, Wim, (i64)(t1a + 1) * FB, lane, L, hr, hi2, wr, wi);
        softmax8(wr);
        softmax8(wi);
        fft512x2<1>(hr, hi2, wr, wi, lane, L, w1c, w1s, w2c, w2s);
#pragma unroll
        for (int j = 0; j < 8; ++j) {
            p1r[j] = (hr[j] * wr[j] - hi2[j] * wi[j]) * (1.0f / 512.0f);
            p1i[j] = (hr[j] * wi[j] + hi2[j] * wr[j]) * (1.0f / 512.0f);
        }
    }
    fft512x2<-1>(p0r, p0i, p1r, p1i, lane, L, w1c, w1s, w2c, w2s);

    // post-transpose -> contiguous f16x8 (16B/lane) stores
    {
        const int a = lane & 7, bq = lane >> 3;
#pragma unroll
        for (int s = 0; s < 8; ++s)
            L[swz(bq + 8 * s, a)] = make_float4(p0r[s], p0i[s], p1r[s], p1i[s]);
    }
    f16x8 o0r, o0i, o1r, o1i;
#pragma unroll
    for (int j = 0; j < 8; ++j) {
        const float4 g = L[swz(lane, j)];
        o0r[j] = (f16)g.x; o0i[j] = (f16)g.y;
        o1r[j] = (f16)g.z; o1i[j] = (f16)g.w;
    }
    *(f16x8*)(Cre + (i64)t1a * FB + 8 * lane) = o0r;
    *(f16x8*)(Cim + (i64)t1a * FB + 8 * lane) = o0i;
    *(f16x8*)(Cre + (i64)(t1a + 1) * FB + 8 * lane) = o1r;
    *(f16x8*)(Cim + (i64)(t1a + 1) * FB + 8 * lane) = o1i;
}

// Single-pass fftconv over all 128 pairs, XCD-swizzled (r13).
__global__ __launch_bounds__(256, 2) void k_fftconv_all(const f16* __restrict__ xh,
                                                        const f16* __restrict__ logits,
                                                        f16* __restrict__ conv) {
    __shared__ float4 LDS[4][512];   // 32 KB -> 5 blocks/CU
    const int id = blockIdx.x;
    const int xcd = id & 7, r = id >> 3;
    const int tblk = r & 31;
    const int cs = (xcd << 4) | (r >> 5);
    const int wave = threadIdx.x >> 6, lane = threadIdx.x & 63;
    fftconv_block(xh, logits, conv, tblk, cs, wave, lane, LDS[wave]);
}

// transpose_out: f16 [t][f] conv plane p -> f32 [f][t] out plane p
__global__ __launch_bounds__(256) void k_transpose_out(const f16* __restrict__ C,
                                                       float* __restrict__ O) {
    __shared__ float ld[64][65];
    const int tid = threadIdx.x;
    const int p = blockIdx.z;
    const f16* src = C + (i64)p * PLANE;
    float* dst = O + (i64)p * PLANE;
    const int t0 = blockIdx.x * 64, f0 = blockIdx.y * 64;
    const int tr = tid >> 3, fc = (tid & 7) * 8;
    f16x8 u0 = *(const f16x8*)&src[(i64)(t0 + tr) * FB + f0 + fc];
    f16x8 u1 = *(const f16x8*)&src[(i64)(t0 + tr + 32) * FB + f0 + fc];
#pragma unroll
    for (int j = 0; j < 8; ++j) {
        ld[fc + j][tr] = (float)u0[j];
        ld[fc + j][tr + 32] = (float)u1[j];
    }
    __syncthreads();
    const int fr = tid >> 4, tc = (tid & 15) * 4;
#pragma unroll
    for (int i = 0; i < 4; ++i) {
        const int f = fr + i * 16;
        float4 o;
        o.x = ld[f][tc + 0]; o.y = ld[f][tc + 1];
        o.z = ld[f][tc + 2]; o.w = ld[f][tc + 3];
        *(float4*)&dst[(i64)(f0 + f) * TB + t0 + tc] = o;
    }
}

extern "C" void kernel_launch(void* const* d_in, const int* in_sizes, int n_in,
                              void* d_out, int out_size, void* d_ws, size_t ws_size,
                              hipStream_t stream) {
    (void)in_sizes; (void)n_in; (void)out_size; (void)ws_size;
    const float* x = (const float*)d_in[0];
    const float* W1 = (const float*)d_in[1];
    const float* b1 = (const float*)d_in[2];
    const float* W2 = (const float*)d_in[3];
    const float* b2 = (const float*)d_in[4];
    float* out = (float*)d_out;

    char* ws = (char*)d_ws;
    const i64 TENB = (i64)67108864;                       // f16 full tensor bytes
    f16* Weff  = (f16*)(ws);                              // 512 KB
    float* beff = (float*)(ws + 524288);                  // 2 KB (pad to 4 KB)
    f16* W1t  = (f16*)(ws + 528384);                      // 512 KB
    f16* W2h  = (f16*)(ws + 1052672);                     // 512 KB
    float* zrs = (float*)(ws + 1576960);                  // 2 KB (pad to 4 KB)
    f16* xh     = (f16*)(ws + 1581056);                   // 67.1 MB
    f16* logits = (f16*)(ws + 1581056 + TENB);            // 67.1 MB
    f16* conv   = (f16*)(ws + 1581056 + 2 * TENB);        // 67.1 MB

    // L1: x-tcvt || W1^T-tcvt || W2-cvt || zeros || beff (wave-parallel)
    k_pre2<<<dim3(8513), dim3(256), 0, stream>>>(x, xh, W1, W1t, W2, W2h, zrs, b1, b2, beff);
    // L2: Weff = W2 @ W1 via MFMA
    k_rgemm<<<dim3(4, 4, 1), dim3(256), 0, stream>>>(W1t, W2h, zrs, Weff);
    // L3: logits = Weff @ X + beff (XCD-grouped: In-tile shared via L2)
    k_rgemm_swz<<<dim3(2048), dim3(256), 0, stream>>>(Weff, xh, beff, logits);
    // L4: fftconv all 128 pairs -> conv f16 (201 MB working set, L3-fit)
    k_fftconv_all<<<dim3(4096), dim3(256), 0, stream>>>(xh, logits, conv);
    // L5: transpose conv -> out (f32 [f][t], all 256 planes)
    k_transpose_out<<<dim3(4, 8, 256), dim3(256), 0, stream>>>(conv, out);
}

// Round 16
// 208.175 us; speedup vs baseline: 1.3833x; 1.0476x over previous
//
#include <hip/hip_runtime.h>
#include <math.h>

#define FB 512
#define TB 256
#define PLANE (FB * TB)
typedef long long i64;
typedef _Float16 f16;
typedef _Float16 f16x8 __attribute__((ext_vector_type(8)));
typedef _Float16 f16x4 __attribute__((ext_vector_type(4)));
typedef float f32x4 __attribute__((ext_vector_type(4)));

#define MFMA16(a, b, c) __builtin_amdgcn_mfma_f32_16x16x32_f16(a, b, c, 0, 0, 0)

// ---------- generic 64x64 transpose+cvt tile: dst[c0+t][r0+f] = src[r0+f][c0+t]
__device__ __forceinline__ void tcvt_tile(const float* __restrict__ src,
                                          f16* __restrict__ dst,
                                          int sstride, int dstride,
                                          int r0, int c0, int tid,
                                          float (*ld)[65]) {
    const int lrr = tid >> 4, lc = (tid & 15) * 4;
    f32x4 v0 = *(const f32x4*)&src[(i64)(r0 + lrr + 0) * sstride + c0 + lc];
    f32x4 v1 = *(const f32x4*)&src[(i64)(r0 + lrr + 16) * sstride + c0 + lc];
    f32x4 v2 = *(const f32x4*)&src[(i64)(r0 + lrr + 32) * sstride + c0 + lc];
    f32x4 v3 = *(const f32x4*)&src[(i64)(r0 + lrr + 48) * sstride + c0 + lc];
#pragma unroll
    for (int j = 0; j < 4; ++j) {
        ld[lrr + 0][lc + j] = v0[j];
        ld[lrr + 16][lc + j] = v1[j];
        ld[lrr + 32][lc + j] = v2[j];
        ld[lrr + 48][lc + j] = v3[j];
    }
    __syncthreads();
    const int tr2 = tid >> 3, fc = (tid & 7) * 8;
#pragma unroll
    for (int pass = 0; pass < 2; ++pass) {
        const int t = tr2 + pass * 32;
        f16x8 o;
#pragma unroll
        for (int j = 0; j < 8; ++j) o[j] = (f16)ld[fc + j][t];
        *(f16x8*)&dst[(i64)(c0 + t) * dstride + r0 + fc] = o;
    }
}

// ================= prologue: x-tcvt || W1^T-tcvt || W2 cvt || zeros || beff ===
__global__ __launch_bounds__(256) void k_pre2(const float* __restrict__ X,
                                              f16* __restrict__ O,
                                              const float* __restrict__ W1,
                                              f16* __restrict__ W1t,
                                              const float* __restrict__ W2,
                                              f16* __restrict__ W2h,
                                              float* __restrict__ zrs,
                                              const float* __restrict__ b1,
                                              const float* __restrict__ b2,
                                              float* __restrict__ beff) {
    __shared__ float ld[64][65];
    const int bid = blockIdx.x;
    const int tid = threadIdx.x;
    if (bid < 8192) {
        const int p = bid >> 5;
        const int f0 = ((bid >> 2) & 7) * 64, t0 = (bid & 3) * 64;
        tcvt_tile(X + (i64)p * PLANE, O + (i64)p * PLANE, TB, FB, f0, t0, tid, ld);
    } else if (bid < 8256) {
        const int w = bid - 8192;
        tcvt_tile(W1, W1t, FB, FB, (w >> 3) * 64, (w & 7) * 64, tid, ld);
    } else if (bid < 8384) {
        const i64 idx = ((i64)(bid - 8256) * 256 + tid) * 8;
        const float4 a = *(const float4*)&W2[idx];
        const float4 b = *(const float4*)&W2[idx + 4];
        f16x8 o;
        o[0] = (f16)a.x; o[1] = (f16)a.y; o[2] = (f16)a.z; o[3] = (f16)a.w;
        o[4] = (f16)b.x; o[5] = (f16)b.y; o[6] = (f16)b.z; o[7] = (f16)b.w;
        *(f16x8*)&W2h[idx] = o;
    } else if (bid == 8384) {
        zrs[tid] = 0.f;
        zrs[tid + 256] = 0.f;
    } else {
        // beff[m] = dot(W2[m,:], b1) + b2[m]; one m per wave, coalesced.
        const int m = (bid - 8385) * 4 + (tid >> 6);
        const int lane = tid & 63;
        const float* w2r = W2 + (i64)m * FB + lane * 8;
        const f32x4 a0 = *(const f32x4*)(w2r);
        const f32x4 a1 = *(const f32x4*)(w2r + 4);
        const f32x4 c0 = *(const f32x4*)(b1 + lane * 8);
        const f32x4 c1 = *(const f32x4*)(b1 + lane * 8 + 4);
        float acc = 0.f;
#pragma unroll
        for (int j = 0; j < 4; ++j) acc = fmaf(a0[j], c0[j], acc);
#pragma unroll
        for (int j = 0; j < 4; ++j) acc = fmaf(a1[j], c1[j], acc);
#pragma unroll
        for (int o = 32; o > 0; o >>= 1) acc += __shfl_xor(acc, o);
        if (lane == 0) beff[m] = acc + b2[m];
    }
}

// ---------- real MFMA GEMM body: Out[t][m] (f16) = sum_k A[m][k]*In[t][k] + bias[m]
__device__ __forceinline__ void rgemm_body(const f16* __restrict__ A,
                                           const f16* __restrict__ In,
                                           const float* __restrict__ bias,
                                           f16* __restrict__ Out,
                                           int t0, int m0, int slab,
                                           f16 (*Asx)[40], f16 (*Bsx)[40]) {
    const f16* Bsrc = In + (i64)slab * PLANE;
    f16* Odst = Out + (i64)slab * PLANE;
    const int tid = threadIdx.x;
    const int wave = tid >> 6, lane = tid & 63;
    const int wm = wave >> 1, wn = wave & 1;
    const int lr = lane & 15, lg = lane >> 4;
    const int srow = tid >> 2, sgrp = (tid & 3) * 8;

    f32x4 acc[4][4] = {};
    f16x8 nA[2], nB[2];
#pragma unroll
    for (int i = 0; i < 2; ++i) {
        const int row = i * 64 + srow;
        nA[i] = *(const f16x8*)(A + (i64)(m0 + row) * FB + sgrp);
        nB[i] = *(const f16x8*)(Bsrc + (i64)(t0 + row) * FB + sgrp);
    }
#pragma unroll
    for (int i = 0; i < 2; ++i) {
        const int row = i * 64 + srow;
        *(f16x8*)&Asx[row][sgrp] = nA[i];
        *(f16x8*)&Bsx[row][sgrp] = nB[i];
    }
    __syncthreads();

#pragma unroll 1
    for (int kt = 0; kt < 16; ++kt) {
        if (kt < 15) {
            const int k0 = (kt + 1) * 32;
#pragma unroll
            for (int i = 0; i < 2; ++i) {
                const int row = i * 64 + srow;
                nA[i] = *(const f16x8*)(A + (i64)(m0 + row) * FB + k0 + sgrp);
                nB[i] = *(const f16x8*)(Bsrc + (i64)(t0 + row) * FB + k0 + sgrp);
            }
        }
        f16x8 aA[4], bB[4];
#pragma unroll
        for (int mf = 0; mf < 4; ++mf)
            aA[mf] = *(const f16x8*)&Asx[wm * 64 + mf * 16 + lr][lg * 8];
#pragma unroll
        for (int nf = 0; nf < 4; ++nf)
            bB[nf] = *(const f16x8*)&Bsx[wn * 64 + nf * 16 + lr][lg * 8];
#pragma unroll
        for (int nf = 0; nf < 4; ++nf)
#pragma unroll
            for (int mf = 0; mf < 4; ++mf)
                acc[mf][nf] = MFMA16(aA[mf], bB[nf], acc[mf][nf]);
        __syncthreads();
        if (kt < 15) {
#pragma unroll
            for (int i = 0; i < 2; ++i) {
                const int row = i * 64 + srow;
                *(f16x8*)&Asx[row][sgrp] = nA[i];
                *(f16x8*)&Bsx[row][sgrp] = nB[i];
            }
        }
        __syncthreads();
    }

#pragma unroll
    for (int mf = 0; mf < 4; ++mf) {
        const int m = m0 + wm * 64 + mf * 16 + lg * 4;
        const float4 bv = *(const float4*)&bias[m];
        const float bb[4] = {bv.x, bv.y, bv.z, bv.w};
#pragma unroll
        for (int nf = 0; nf < 4; ++nf) {
            const int t = t0 + wn * 64 + nf * 16 + lr;
            f16x4 o;
#pragma unroll
            for (int r = 0; r < 4; ++r) o[r] = (f16)(acc[mf][nf][r] + bb[r]);
            *(f16x4*)&Odst[(i64)t * FB + m] = o;
        }
    }
}

// 3D-grid launcher (used for Weff = W2@W1: A=W1t, In=W2h, bias=0)
__global__ __launch_bounds__(256, 2) void k_rgemm(const f16* __restrict__ A,
                                                  const f16* __restrict__ In,
                                                  const float* __restrict__ bias,
                                                  f16* __restrict__ Out) {
    __shared__ f16 Asx[128][40], Bsx[128][40];
    rgemm_body(A, In, bias, Out, blockIdx.x * 128, blockIdx.y * 128, blockIdx.z,
               Asx, Bsx);
}

// XCD-grouped 1D launcher for logits GEMM (r13: +L2 tile reuse)
__global__ __launch_bounds__(256, 2) void k_rgemm_swz(const f16* __restrict__ A,
                                                      const f16* __restrict__ In,
                                                      const float* __restrict__ bias,
                                                      f16* __restrict__ Out) {
    __shared__ f16 Asx[128][40], Bsx[128][40];
    const int id = blockIdx.x;
    const int xcd = id & 7, q = id >> 3;
    const int m = q & 3;
    const int G = ((q >> 2) << 3) | xcd;
    rgemm_body(A, In, bias, Out, (G & 1) * 128, m * 128, G >> 1, Asx, Bsx);
}

// ================= fused softmax + conjFFT/mul/FFT, radix-8 three-step =======
// FFT arrangement: z[p] at (lane=p%64, reg=p/64). Global I/O is DIRECT in this
// arrangement: instruction j touches addr base+lane+64j -> lane-stride 1
// element = 128B contiguous per instruction (coalesced). r9's marshal "fix"
// was based on a wrong fragmentation theory; removing it cuts LDS traffic
// 144->96 b128 ops/thread and 4 lgkmcnt chains per block.
// Internal transposes use XOR-swizzled 64x8-float4 grid (32 KB/block).

#define TWO_PI_OVER_512 0.012271846303085129f
#define TWO_PI_OVER_64 0.0981747704246810387f
#define R2C 0.70710678118654752f

__device__ __forceinline__ int swz(int r, int c) { return r * 8 + (c ^ (r & 7)); }

template <int SGN>
__device__ __forceinline__ void fft8(float xr[8], float xi[8]) {
    const float sg = (float)SGN;   // W8 = e^{SGN*i*2pi/8}
    float t0r = xr[0] + xr[4], t0i = xi[0] + xi[4];
    float u0r = xr[0] - xr[4], u0i = xi[0] - xi[4];
    float t1r = xr[1] + xr[5], t1i = xi[1] + xi[5];
    float d1r = xr[1] - xr[5], d1i = xi[1] - xi[5];
    float u1r = R2C * (d1r - sg * d1i), u1i = R2C * (sg * d1r + d1i);
    float t2r = xr[2] + xr[6], t2i = xi[2] + xi[6];
    float d2r = xr[2] - xr[6], d2i = xi[2] - xi[6];
    float u2r = -sg * d2i, u2i = sg * d2r;
    float t3r = xr[3] + xr[7], t3i = xi[3] + xi[7];
    float d3r = xr[3] - xr[7], d3i = xi[3] - xi[7];
    float u3r = -R2C * (d3r + sg * d3i), u3i = R2C * (sg * d3r - d3i);
    float p0r = t0r + t2r, p0i = t0i + t2i, q0r = t0r - t2r, q0i = t0i - t2i;
    float p1r = t1r + t3r, p1i = t1i + t3i;
    float q1r = -sg * (t1i - t3i), q1i = sg * (t1r - t3r);
    float p2r = u0r + u2r, p2i = u0i + u2i, q2r = u0r - u2r, q2i = u0i - u2i;
    float p3r = u1r + u3r, p3i = u1i + u3i;
    float q3r = -sg * (u1i - u3i), q3i = sg * (u1r - u3r);
    xr[0] = p0r + p1r; xi[0] = p0i + p1i;
    xr[4] = p0r - p1r; xi[4] = p0i - p1i;
    xr[2] = q0r + q1r; xi[2] = q0i + q1i;
    xr[6] = q0r - q1r; xi[6] = q0i - q1i;
    xr[1] = p2r + p3r; xi[1] = p2i + p3i;
    xr[5] = p2r - p3r; xi[5] = p2i - p3i;
    xr[3] = q2r + q3r; xi[3] = q2i + q3i;
    xr[7] = q2r - q3r; xi[7] = q2i - q3i;
}

template <int SGN>
__device__ __forceinline__ void fft512x2(float ar[8], float ai[8],
                                         float br[8], float bi[8], int lane,
                                         float4* __restrict__ L,
                                         const float w1c[7], const float w1s[7],
                                         const float w2c[7], const float w2s[7]) {
    const float sg = (float)SGN;
    fft8<SGN>(ar, ai);
    fft8<SGN>(br, bi);
#pragma unroll
    for (int m = 1; m < 8; ++m) {
        const float wc = w1c[m - 1], ws = sg * w1s[m - 1];
        float tr = ar[m], ti = ai[m];
        ar[m] = tr * wc - ti * ws; ai[m] = tr * ws + ti * wc;
        tr = br[m]; ti = bi[m];
        br[m] = tr * wc - ti * ws; bi[m] = tr * ws + ti * wc;
    }
    // transpose 1: linear write (lane, m) ; permuted read (a8+8b8, m8)
#pragma unroll
    for (int m = 0; m < 8; ++m)
        L[swz(lane, m)] = make_float4(ar[m], ai[m], br[m], bi[m]);
    {
        const int a8 = lane & 7, m8 = lane >> 3;
#pragma unroll
        for (int b8 = 0; b8 < 8; ++b8) {
            const float4 v = L[swz(a8 + 8 * b8, m8)];
            ar[b8] = v.x; ai[b8] = v.y; br[b8] = v.z; bi[b8] = v.w;
        }
    }
    fft8<SGN>(ar, ai);
    fft8<SGN>(br, bi);
#pragma unroll
    for (int n = 1; n < 8; ++n) {
        const float wc = w2c[n - 1], ws = sg * w2s[n - 1];
        float tr = ar[n], ti = ai[n];
        ar[n] = tr * wc - ti * ws; ai[n] = tr * ws + ti * wc;
        tr = br[n]; ti = bi[n];
        br[n] = tr * wc - ti * ws; bi[n] = tr * ws + ti * wc;
    }
    // transpose 2: scatter write (m2+8n, a2) ; linear read (lane, j)
    {
        const int a2 = lane & 7, m2 = lane >> 3;
#pragma unroll
        for (int n = 0; n < 8; ++n)
            L[swz(m2 + 8 * n, a2)] = make_float4(ar[n], ai[n], br[n], bi[n]);
    }
#pragma unroll
    for (int j = 0; j < 8; ++j) {
        const float4 v = L[swz(lane, j)];
        ar[j] = v.x; ai[j] = v.y; br[j] = v.z; bi[j] = v.w;
    }
    fft8<SGN>(ar, ai);
    fft8<SGN>(br, bi);
}

__device__ __forceinline__ float wave_max(float v) {
#pragma unroll
    for (int m = 1; m <= 32; m <<= 1) v = fmaxf(v, __shfl_xor(v, m));
    return v;
}
__device__ __forceinline__ float wave_sum(float v) {
#pragma unroll
    for (int m = 1; m <= 32; m <<= 1) v += __shfl_xor(v, m);
    return v;
}

__device__ __forceinline__ void softmax8(float w[8]) {
    float mx = w[0];
#pragma unroll
    for (int j = 1; j < 8; ++j) mx = fmaxf(mx, w[j]);
    mx = wave_max(mx);
    float sm = 0.f;
#pragma unroll
    for (int j = 0; j < 8; ++j) { w[j] = __expf(w[j] - mx); sm += w[j]; }
    sm = wave_sum(sm);
    const float inv = 1.0f / sm;
#pragma unroll
    for (int j = 0; j < 8; ++j) w[j] *= inv;
}

__device__ __forceinline__ void fftconv_block(const f16* __restrict__ xh,
                                              const f16* __restrict__ logits,
                                              f16* __restrict__ conv,
                                              int tblk, int cs,
                                              int wave, int lane, float4* L) {
    const int b = cs >> 4, d = cs & 15;
    const int pre = b * 32 + d;
    const int pim = pre + 16;

    float w1c[7], w1s[7], w2c[7], w2s[7];
    {
        float s1, c1;
        __sincosf((float)lane * TWO_PI_OVER_512, &s1, &c1);
        w1c[0] = c1; w1s[0] = s1;
#pragma unroll
        for (int m = 1; m < 7; ++m) {
            const float pc = w1c[m - 1], ps = w1s[m - 1];
            w1c[m] = pc * c1 - ps * s1;
            w1s[m] = pc * s1 + ps * c1;
        }
        float s2, c2;
        __sincosf((float)(lane & 7) * TWO_PI_OVER_64, &s2, &c2);
        w2c[0] = c2; w2s[0] = s2;
#pragma unroll
        for (int n = 1; n < 7; ++n) {
            const float pc = w2c[n - 1], ps = w2s[n - 1];
            w2c[n] = pc * c2 - ps * s2;
            w2s[n] = pc * s2 + ps * c2;
        }
    }

    const f16* Hre = xh + (i64)pre * PLANE;
    const f16* Him = xh + (i64)pim * PLANE;
    const f16* Wre = logits + (i64)pre * PLANE;
    const f16* Wim = logits + (i64)pim * PLANE;
    f16* Cre = conv + (i64)pre * PLANE;
    f16* Cim = conv + (i64)pim * PLANE;

    const int t1a = tblk * 8 + wave * 2;
    const i64 rb0 = (i64)t1a * FB + lane;
    const i64 rb1 = rb0 + FB;

    float p0r[8], p0i[8], p1r[8], p1i[8];
    {
        float hr[8], hi2[8], wr[8], wi[8];
#pragma unroll
        for (int j = 0; j < 8; ++j) {
            hr[j] = (float)Hre[rb0 + 64 * j];
            hi2[j] = (float)Him[rb0 + 64 * j];
            wr[j] = (float)Wre[rb0 + 64 * j];
            wi[j] = (float)Wim[rb0 + 64 * j];
        }
        softmax8(wr);
        softmax8(wi);
        fft512x2<1>(hr, hi2, wr, wi, lane, L, w1c, w1s, w2c, w2s);
#pragma unroll
        for (int j = 0; j < 8; ++j) {
            p0r[j] = (hr[j] * wr[j] - hi2[j] * wi[j]) * (1.0f / 512.0f);
            p0i[j] = (hr[j] * wi[j] + hi2[j] * wr[j]) * (1.0f / 512.0f);
        }
    }
    {
        float hr[8], hi2[8], wr[8], wi[8];
#pragma unroll
        for (int j = 0; j < 8; ++j) {
            hr[j] = (float)Hre[rb1 + 64 * j];
            hi2[j] = (float)Him[rb1 + 64 * j];
            wr[j] = (float)Wre[rb1 + 64 * j];
            wi[j] = (float)Wim[rb1 + 64 * j];
        }
        softmax8(wr);
        softmax8(wi);
        fft512x2<1>(hr, hi2, wr, wi, lane, L, w1c, w1s, w2c, w2s);
#pragma unroll
        for (int j = 0; j < 8; ++j) {
            p1r[j] = (hr[j] * wr[j] - hi2[j] * wi[j]) * (1.0f / 512.0f);
            p1i[j] = (hr[j] * wi[j] + hi2[j] * wr[j]) * (1.0f / 512.0f);
        }
    }
    fft512x2<-1>(p0r, p0i, p1r, p1i, lane, L, w1c, w1s, w2c, w2s);

    // direct coalesced stores: instruction s covers 128B contiguous per wave
#pragma unroll
    for (int s = 0; s < 8; ++s) {
        Cre[rb0 + 64 * s] = (f16)p0r[s];
        Cim[rb0 + 64 * s] = (f16)p0i[s];
        Cre[rb1 + 64 * s] = (f16)p1r[s];
        Cim[rb1 + 64 * s] = (f16)p1i[s];
    }
}

// Single-pass fftconv over all 128 pairs, XCD-swizzled (r13).
__global__ __launch_bounds__(256, 2) void k_fftconv_all(const f16* __restrict__ xh,
                                                        const f16* __restrict__ logits,
                                                        f16* __restrict__ conv) {
    __shared__ float4 LDS[4][512];   // 32 KB
    const int id = blockIdx.x;
    const int xcd = id & 7, r = id >> 3;
    const int tblk = r & 31;
    const int cs = (xcd << 4) | (r >> 5);
    const int wave = threadIdx.x >> 6, lane = threadIdx.x & 63;
    fftconv_block(xh, logits, conv, tblk, cs, wave, lane, LDS[wave]);
}

// transpose_out: f16 [t][f] conv plane p -> f32 [f][t] out plane p
__global__ __launch_bounds__(256) void k_transpose_out(const f16* __restrict__ C,
                                                       float* __restrict__ O) {
    __shared__ float ld[64][65];
    const int tid = threadIdx.x;
    const int p = blockIdx.z;
    const f16* src = C + (i64)p * PLANE;
    float* dst = O + (i64)p * PLANE;
    const int t0 = blockIdx.x * 64, f0 = blockIdx.y * 64;
    const int tr = tid >> 3, fc = (tid & 7) * 8;
    f16x8 u0 = *(const f16x8*)&src[(i64)(t0 + tr) * FB + f0 + fc];
    f16x8 u1 = *(const f16x8*)&src[(i64)(t0 + tr + 32) * FB + f0 + fc];
#pragma unroll
    for (int j = 0; j < 8; ++j) {
        ld[fc + j][tr] = (float)u0[j];
        ld[fc + j][tr + 32] = (float)u1[j];
    }
    __syncthreads();
    const int fr = tid >> 4, tc = (tid & 15) * 4;
#pragma unroll
    for (int i = 0; i < 4; ++i) {
        const int f = fr + i * 16;
        float4 o;
        o.x = ld[f][tc + 0]; o.y = ld[f][tc + 1];
        o.z = ld[f][tc + 2]; o.w = ld[f][tc + 3];
        *(float4*)&dst[(i64)(f0 + f) * TB + t0 + tc] = o;
    }
}

extern "C" void kernel_launch(void* const* d_in, const int* in_sizes, int n_in,
                              void* d_out, int out_size, void* d_ws, size_t ws_size,
                              hipStream_t stream) {
    (void)in_sizes; (void)n_in; (void)out_size; (void)ws_size;
    const float* x = (const float*)d_in[0];
    const float* W1 = (const float*)d_in[1];
    const float* b1 = (const float*)d_in[2];
    const float* W2 = (const float*)d_in[3];
    const float* b2 = (const float*)d_in[4];
    float* out = (float*)d_out;

    char* ws = (char*)d_ws;
    const i64 TENB = (i64)67108864;                       // f16 full tensor bytes
    f16* Weff  = (f16*)(ws);                              // 512 KB
    float* beff = (float*)(ws + 524288);                  // 2 KB (pad to 4 KB)
    f16* W1t  = (f16*)(ws + 528384);                      // 512 KB
    f16* W2h  = (f16*)(ws + 1052672);                     // 512 KB
    float* zrs = (float*)(ws + 1576960);                  // 2 KB (pad to 4 KB)
    f16* xh     = (f16*)(ws + 1581056);                   // 67.1 MB
    f16* logits = (f16*)(ws + 1581056 + TENB);            // 67.1 MB
    f16* conv   = (f16*)(ws + 1581056 + 2 * TENB);        // 67.1 MB

    // L1: x-tcvt || W1^T-tcvt || W2-cvt || zeros || beff (wave-parallel)
    k_pre2<<<dim3(8513), dim3(256), 0, stream>>>(x, xh, W1, W1t, W2, W2h, zrs, b1, b2, beff);
    // L2: Weff = W2 @ W1 via MFMA
    k_rgemm<<<dim3(4, 4, 1), dim3(256), 0, stream>>>(W1t, W2h, zrs, Weff);
    // L3: logits = Weff @ X + beff (XCD-grouped: In-tile shared via L2)
    k_rgemm_swz<<<dim3(2048), dim3(256), 0, stream>>>(Weff, xh, beff, logits);
    // L4: fftconv all 128 pairs -> conv f16 (201 MB working set, L3-fit)
    k_fftconv_all<<<dim3(4096), dim3(256), 0, stream>>>(xh, logits, conv);
    // L5: transpose conv -> out (f32 [f][t], all 256 planes)
    k_transpose_out<<<dim3(4, 8, 256), dim3(256), 0, stream>>>(conv, out);
}